// Round 1
// baseline (3024.232 us; speedup 1.0000x reference)
//
#include <hip/hip_runtime.h>
#include <stdint.h>
#include <stddef.h>

#define B_DIM   1024
#define DIN     512
#define H_DIM   768
#define A_DIM   5001
#define NHEADS  2
#define NSTEPS  4
#define C_DIM   2
#define NEG_VAL -1e30f

// ------------------------- Threefry-2x32 (JAX-compatible) -------------------------
__host__ __device__ inline uint32_t rotl32(uint32_t x, int d) {
  return (x << d) | (x >> (32 - d));
}

__host__ __device__ inline void threefry2x32(uint32_t k0, uint32_t k1,
                                             uint32_t x0, uint32_t x1,
                                             uint32_t& o0, uint32_t& o1) {
  uint32_t ks2 = k0 ^ k1 ^ 0x1BD11BDAu;
  x0 += k0; x1 += k1;
#define TFR(d) { x0 += x1; x1 = rotl32(x1, (d)); x1 ^= x0; }
  TFR(13) TFR(15) TFR(26) TFR(6)  x0 += k1;  x1 += ks2 + 1u;
  TFR(17) TFR(29) TFR(16) TFR(24) x0 += ks2; x1 += k0 + 2u;
  TFR(13) TFR(15) TFR(26) TFR(6)  x0 += k0;  x1 += k1 + 3u;
  TFR(17) TFR(29) TFR(16) TFR(24) x0 += k1;  x1 += ks2 + 4u;
  TFR(13) TFR(15) TFR(26) TFR(6)  x0 += ks2; x1 += k0 + 5u;
#undef TFR
  o0 = x0; o1 = x1;
}

// JAX partitionable threefry random_bits for 32-bit draws: bits = o0 ^ o1 with
// counter (hi=0, lo=idx) for sizes < 2^32.
__device__ inline float gumbel_noise(uint32_t k0, uint32_t k1, uint32_t idx) {
  uint32_t o0, o1;
  threefry2x32(k0, k1, 0u, idx, o0, o1);
  uint32_t bits = o0 ^ o1;
  float f = __uint_as_float(0x3f800000u | (bits >> 9)) - 1.0f;   // [0,1)
  float u = fmaxf(1e-9f, f * (1.0f - 1e-9f) + 1e-9f);            // jax.random.uniform
  return -logf(-logf(u));                                        // Gumbel(0,1)
}

// XLA logistic lowering: 0.5 + 0.5 * tanh(0.5 * x)
__device__ inline float sigmoidf_(float x) { return 0.5f * tanhf(0.5f * x) + 0.5f; }

// ------------------------- fp32 tiled GEMM: C = A[M,K] @ B[K,N] + bias, act -------------------------
// BM=BN=64, BK=16, 256 threads, 4x4 per thread. M % 64 == 0, K % 16 == 0; N guarded.
__global__ __launch_bounds__(256) void gemm_bias_act(
    const float* __restrict__ A, const float* __restrict__ B,
    const float* __restrict__ bias, float* __restrict__ C,
    int M, int N, int K, int act) {
  __shared__ float As[16][65];   // [k][m], padded to break 16-way write conflict
  __shared__ float Bs[16][64];   // [k][n]
  int tid = threadIdx.x;
  int bm = blockIdx.y * 64, bn = blockIdx.x * 64;
  int tx = tid & 15, ty = tid >> 4;
  float acc[4][4] = {};
  for (int k0 = 0; k0 < K; k0 += 16) {
#pragma unroll
    for (int r = 0; r < 4; ++r) {
      int m = (tid >> 4) + r * 16;
      int k = tid & 15;
      As[k][m] = A[(size_t)(bm + m) * K + k0 + k];
    }
#pragma unroll
    for (int r = 0; r < 4; ++r) {
      int n = tid & 63;
      int k = (tid >> 6) + r * 4;
      int gn = bn + n;
      Bs[k][n] = (gn < N) ? B[(size_t)(k0 + k) * N + gn] : 0.0f;
    }
    __syncthreads();
#pragma unroll
    for (int kk = 0; kk < 16; ++kk) {
      float a[4], bb[4];
#pragma unroll
      for (int i = 0; i < 4; ++i) a[i] = As[kk][ty * 4 + i];
#pragma unroll
      for (int jj = 0; jj < 4; ++jj) bb[jj] = Bs[kk][tx * 4 + jj];
#pragma unroll
      for (int i = 0; i < 4; ++i)
#pragma unroll
        for (int jj = 0; jj < 4; ++jj) acc[i][jj] = fmaf(a[i], bb[jj], acc[i][jj]);
    }
    __syncthreads();
  }
#pragma unroll
  for (int i = 0; i < 4; ++i) {
    int m = bm + ty * 4 + i;
#pragma unroll
    for (int jj = 0; jj < 4; ++jj) {
      int n = bn + tx * 4 + jj;
      if (n < N) {
        float v = acc[i][jj] + bias[n];
        if (act == 1) v = fmaxf(v, 0.0f);
        C[(size_t)m * N + n] = v;
      }
    }
  }
}

// ------------------------- GRU gate combine -------------------------
__global__ __launch_bounds__(256) void gru_combine_kernel(
    const float* __restrict__ gi, const float* __restrict__ gh, float* __restrict__ h) {
  int idx = blockIdx.x * blockDim.x + threadIdx.x;
  if (idx >= B_DIM * H_DIM) return;
  int b = idx / H_DIM, c = idx - b * H_DIM;
  const float* gib = gi + (size_t)b * 3 * H_DIM;
  const float* ghb = gh + (size_t)b * 3 * H_DIM;
  float ir = gib[c], iz = gib[H_DIM + c], inn = gib[2 * H_DIM + c];
  float hr = ghb[c], hz = ghb[H_DIM + c], hn = ghb[2 * H_DIM + c];
  float r = sigmoidf_(ir + hr);
  float z = sigmoidf_(iz + hz);
  float n = tanhf(inn + r * hn);
  h[idx] = (1.0f - z) * n + z * h[idx];
}

// ------------------------- cur_in = cls + ae_w[ind] -------------------------
__global__ __launch_bounds__(256) void curin_kernel(
    const float* __restrict__ cls, const float* __restrict__ ae_w,
    const int* __restrict__ ind_buf, int j, float* __restrict__ cur_in) {
  int idx = blockIdx.x * blockDim.x + threadIdx.x;
  if (idx >= B_DIM * H_DIM) return;
  int b = idx / H_DIM, c = idx - b * H_DIM;
  int ind = ind_buf[j * B_DIM + b];
  cur_in[idx] = cls[idx] + ae_w[(size_t)ind * H_DIM + c];
}

// ------------------------- sampling: mask, gumbel, softmax-faithful argmax -------------------------
#define STH 256
#define PER_TH 20  // ceil(5001/256)

__global__ __launch_bounds__(STH) void sample_kernel(
    const float* __restrict__ logits, const int* __restrict__ x_mask,
    int* __restrict__ ind_buf, float* __restrict__ probs,
    int head, int j, uint32_t k0, uint32_t k1) {
  int b = blockIdx.x;
  int t = threadIdx.x;
  __shared__ float rv[STH];
  __shared__ int ri[STH];
  __shared__ int s_ind;

  const float* lrow = logits + (size_t)b * A_DIM;
  const int* mrow = x_mask + (size_t)b * A_DIM;

  // index history -> dead-row flag + chosen exclusion (reconstructs mask evolution)
  int prev[3];
  bool dead = false;
  for (int tt = 0; tt < j; ++tt) {
    prev[tt] = ind_buf[tt * B_DIM + b];
    if (prev[tt] == 0) dead = true;
  }

  bool rowany = true;
  if (j == 0) {  // col0 = (row sum == 0) ? 1 : mask[b,0]
    int any = 0;
    for (int a = t; a < A_DIM; a += STH) any |= mrow[a];
    ri[t] = any; __syncthreads();
    for (int s = STH / 2; s > 0; s >>= 1) {
      if (t < s) ri[t] |= ri[t + s];
      __syncthreads();
    }
    rowany = (ri[0] != 0);
    __syncthreads();
  }

  float v[PER_TH];
  float lmax = -3.0e38f;
#pragma unroll
  for (int s = 0; s < PER_TH; ++s) {
    int a = t + s * STH;
    float val = -3.0e38f;
    if (a < A_DIM) {
      int m;
      if (j == 0) {
        m = (a == 0) ? (rowany ? mrow[0] : 1) : mrow[a];
      } else if (a == 0) {
        m = 1;                       // mask[:,0] = 1 every step j >= 1
      } else if (dead) {
        m = 0;                       // row zeroed once atom 0 was picked
      } else {
        m = mrow[a];
        if (m) {
          for (int tt = 0; tt < j; ++tt)
            if (prev[tt] == a) { m = 0; break; }   // chosen atoms zeroed
        }
      }
      float base = (m > 0) ? lrow[a] : NEG_VAL;
      val = base + gumbel_noise(k0, k1, (uint32_t)(b * A_DIM + a));
    }
    v[s] = val;
    lmax = fmaxf(lmax, val);
  }

  // row max (jnp.max)
  rv[t] = lmax; __syncthreads();
  for (int s = STH / 2; s > 0; s >>= 1) {
    if (t < s) rv[t] = fmaxf(rv[t], rv[t + s]);
    __syncthreads();
  }
  float m = rv[0]; __syncthreads();

  // exp + sum
  float lsum = 0.0f;
#pragma unroll
  for (int s = 0; s < PER_TH; ++s) {
    int a = t + s * STH;
    float e = (a < A_DIM) ? expf(v[s] - m) : 0.0f;
    v[s] = e; lsum += e;
  }
  rv[t] = lsum; __syncthreads();
  for (int s = STH / 2; s > 0; s >>= 1) {
    if (t < s) rv[t] += rv[t + s];
    __syncthreads();
  }
  float ssum = rv[0]; __syncthreads();

  // argmax of y = e / sum, first-occurrence tie-break (matches jnp.argmax on y_soft)
  float besty = -1.0f; int besti = A_DIM;
#pragma unroll
  for (int s = 0; s < PER_TH; ++s) {
    int a = t + s * STH;
    if (a < A_DIM) {
      float y = v[s] / ssum;
      if (y > besty) { besty = y; besti = a; }
    }
  }
  rv[t] = besty; ri[t] = besti; __syncthreads();
  for (int s = STH / 2; s > 0; s >>= 1) {
    if (t < s) {
      float y2 = rv[t + s]; int i2 = ri[t + s];
      if (y2 > rv[t] || (y2 == rv[t] && i2 < ri[t])) { rv[t] = y2; ri[t] = i2; }
    }
    __syncthreads();
  }
  if (t == 0) { s_ind = ri[0]; ind_buf[j * B_DIM + b] = ri[0]; }
  __syncthreads();
  int ind = s_ind;

  // prob = y_hard (exact one-hot in forward)
  float* prow = probs + (((size_t)b * NHEADS + head) * NSTEPS + j) * A_DIM;
  for (int a = t; a < A_DIM; a += STH) prow[a] = (a == ind) ? 1.0f : 0.0f;
}

// ------------------------- per-head consequent estimator -------------------------
__global__ __launch_bounds__(256) void head_final_kernel(
    const int* __restrict__ ind_buf, const float* __restrict__ Wmu,
    const float* __restrict__ bmu, const float* __restrict__ Wcov,
    const float* __restrict__ bcov, const float* __restrict__ alpha,
    float* __restrict__ matcp, int head) {
  int b = blockIdx.x * blockDim.x + threadIdx.x;
  if (b >= B_DIM) return;
  float a0 = 0.0f, a1 = 0.0f, ac = 0.0f;
  for (int j = 0; j < NSTEPS; ++j) {
    int ind = ind_buf[j * B_DIM + b];
    a0 += 0.25f * Wmu[(size_t)ind * C_DIM + 0];
    a1 += 0.25f * Wmu[(size_t)ind * C_DIM + 1];
    ac += 0.25f * Wcov[ind];
  }
  float mu0 = sigmoidf_(a0 + bmu[0]);
  float mu1 = sigmoidf_(a1 + bmu[1]);
  float cov = sigmoidf_(ac + bcov[0]);
  float n = cov * 56000.0f;
  float sf = alpha[0] / n;
  float denom = 1.0f + 2.0f * sf;
  matcp[((size_t)b * NHEADS + head) * C_DIM + 0] = (mu0 + sf) / denom;
  matcp[((size_t)b * NHEADS + head) * C_DIM + 1] = (mu1 + sf) / denom;
}

// ------------------------- final: out = log(mean over heads of cp) -------------------------
__global__ __launch_bounds__(256) void final_out_kernel(
    const float* __restrict__ matcp, float* __restrict__ out) {
  int idx = blockIdx.x * blockDim.x + threadIdx.x;
  if (idx >= B_DIM * C_DIM) return;
  int b = idx / C_DIM, c = idx - b * C_DIM;
  float s = matcp[((size_t)b * NHEADS + 0) * C_DIM + c] +
            matcp[((size_t)b * NHEADS + 1) * C_DIM + c];
  out[idx] = logf(s * 0.5f);
}

// ------------------------- orchestration -------------------------
extern "C" void kernel_launch(void* const* d_in, const int* in_sizes, int n_in,
                              void* d_out, int out_size, void* d_ws, size_t ws_size,
                              hipStream_t stream) {
  const float* x     = (const float*)d_in[0];
  const int*   xmask = (const int*)d_in[1];
  const float* W1 = (const float*)d_in[2];  const float* b1 = (const float*)d_in[3];
  const float* W2 = (const float*)d_in[4];  const float* b2 = (const float*)d_in[5];
  const float* W3 = (const float*)d_in[6];  const float* b3 = (const float*)d_in[7];
  const float* gWih = (const float*)d_in[8];  const float* gWhh = (const float*)d_in[9];
  const float* gbih = (const float*)d_in[10]; const float* gbhh = (const float*)d_in[11];
  const float* hW = (const float*)d_in[12];   const float* hb = (const float*)d_in[13];
  const float* ae_w = (const float*)d_in[14];
  const float* Wmu  = (const float*)d_in[15]; const float* bmu  = (const float*)d_in[16];
  const float* Wcov = (const float*)d_in[17]; const float* bcov = (const float*)d_in[18];
  const float* alpha = (const float*)d_in[19];

  float* out = (float*)d_out;
  float* probs = out + (size_t)B_DIM * C_DIM;
  float* matcp = probs + (size_t)B_DIM * NHEADS * NSTEPS * A_DIM;

  float* cls    = (float*)d_ws;
  float* h      = cls + (size_t)B_DIM * H_DIM;
  float* curin  = h + (size_t)B_DIM * H_DIM;
  float* gi     = curin + (size_t)B_DIM * H_DIM;
  float* gh     = gi + (size_t)B_DIM * 3 * H_DIM;
  float* logits = gh + (size_t)B_DIM * 3 * H_DIM;
  int*   indb   = (int*)(logits + (size_t)B_DIM * A_DIM);

  dim3 blk(256);
  auto gemm = [&](const float* Am, const float* Bm, const float* bias, float* Cm,
                  int M, int N, int K, int act) {
    dim3 grid((N + 63) / 64, M / 64);
    gemm_bias_act<<<grid, blk, 0, stream>>>(Am, Bm, bias, Cm, M, N, K, act);
  };

  // MLP: cls = (relu(relu(x@W1+b1)@W2+b2))@W3 + b3
  gemm(x, W1, b1, h, B_DIM, H_DIM, DIN, 1);
  gemm(h, W2, b2, curin, B_DIM, H_DIM, H_DIM, 1);
  gemm(curin, W3, b3, cls, B_DIM, H_DIM, H_DIM, 0);

  const int bh = B_DIM * H_DIM;
  uint32_t bk0 = 0u, bk1 = 42u;  // jax.random.key(42)
  for (int head = 0; head < NHEADS; ++head) {
    uint32_t hk0, hk1;
    threefry2x32(bk0, bk1, 0u, (uint32_t)head, hk0, hk1);  // fold_in(key, head)
    hipMemsetAsync(h, 0, (size_t)bh * sizeof(float), stream);
    hipMemcpyAsync(curin, cls, (size_t)bh * sizeof(float), hipMemcpyDeviceToDevice, stream);
    for (int j = 0; j < NSTEPS; ++j) {
      uint32_t sk0, sk1;
      threefry2x32(hk0, hk1, 0u, (uint32_t)j, sk0, sk1);   // fold_in(head_key, j)
      const float* Wih = gWih + (size_t)head * H_DIM * 3 * H_DIM;
      const float* Whh = gWhh + (size_t)head * H_DIM * 3 * H_DIM;
      gemm(curin, Wih, gbih + (size_t)head * 3 * H_DIM, gi, B_DIM, 3 * H_DIM, H_DIM, 0);
      gemm(h,     Whh, gbhh + (size_t)head * 3 * H_DIM, gh, B_DIM, 3 * H_DIM, H_DIM, 0);
      gru_combine_kernel<<<(bh + 255) / 256, blk, 0, stream>>>(gi, gh, h);
      gemm(h, hW + (size_t)head * H_DIM * A_DIM, hb + (size_t)head * A_DIM,
           logits, B_DIM, A_DIM, H_DIM, 0);
      sample_kernel<<<B_DIM, STH, 0, stream>>>(logits, xmask, indb, probs, head, j, sk0, sk1);
      if (j < NSTEPS - 1)
        curin_kernel<<<(bh + 255) / 256, blk, 0, stream>>>(cls, ae_w, indb, j, curin);
    }
    head_final_kernel<<<(B_DIM + 255) / 256, blk, 0, stream>>>(
        indb, Wmu, bmu, Wcov, bcov, alpha, matcp, head);
  }
  final_out_kernel<<<(B_DIM * C_DIM + 255) / 256, blk, 0, stream>>>(matcp, out);
}

// Round 2
// 2365.790 us; speedup vs baseline: 1.2783x; 1.2783x over previous
//
#include <hip/hip_runtime.h>
#include <stdint.h>
#include <stddef.h>

#define B_DIM   1024
#define DIN     512
#define H_DIM   768
#define A_DIM   5001
#define NHEADS  2
#define NSTEPS  4
#define C_DIM   2
#define NEG_VAL -1e30f
#define BH      (B_DIM * H_DIM)

// ------------------------- Threefry-2x32 (JAX-compatible) -------------------------
__host__ __device__ inline uint32_t rotl32(uint32_t x, int d) {
  return (x << d) | (x >> (32 - d));
}

__host__ __device__ inline void threefry2x32(uint32_t k0, uint32_t k1,
                                             uint32_t x0, uint32_t x1,
                                             uint32_t& o0, uint32_t& o1) {
  uint32_t ks2 = k0 ^ k1 ^ 0x1BD11BDAu;
  x0 += k0; x1 += k1;
#define TFR(d) { x0 += x1; x1 = rotl32(x1, (d)); x1 ^= x0; }
  TFR(13) TFR(15) TFR(26) TFR(6)  x0 += k1;  x1 += ks2 + 1u;
  TFR(17) TFR(29) TFR(16) TFR(24) x0 += ks2; x1 += k0 + 2u;
  TFR(13) TFR(15) TFR(26) TFR(6)  x0 += k0;  x1 += k1 + 3u;
  TFR(17) TFR(29) TFR(16) TFR(24) x0 += k1;  x1 += ks2 + 4u;
  TFR(13) TFR(15) TFR(26) TFR(6)  x0 += ks2; x1 += k0 + 5u;
#undef TFR
  o0 = x0; o1 = x1;
}

__device__ inline float gumbel_noise(uint32_t k0, uint32_t k1, uint32_t idx) {
  uint32_t o0, o1;
  threefry2x32(k0, k1, 0u, idx, o0, o1);
  uint32_t bits = o0 ^ o1;
  float f = __uint_as_float(0x3f800000u | (bits >> 9)) - 1.0f;   // [0,1)
  float u = fmaxf(1e-9f, f * (1.0f - 1e-9f) + 1e-9f);            // jax.random.uniform
  return -logf(-logf(u));                                        // Gumbel(0,1)
}

// XLA logistic lowering: 0.5 + 0.5 * tanh(0.5 * x)
__device__ inline float sigmoidf_(float x) { return 0.5f * tanhf(0.5f * x) + 0.5f; }

// ------------------------- small fp32 GEMM (MLP): 64x64 tile, 4x4/thread -------------------------
__global__ __launch_bounds__(256) void gemm_bias_act(
    const float* __restrict__ A, const float* __restrict__ B,
    const float* __restrict__ bias, float* __restrict__ C,
    int M, int N, int K, int act) {
  __shared__ float As[16][65];
  __shared__ float Bs[16][64];
  int tid = threadIdx.x;
  int bm = blockIdx.y * 64, bn = blockIdx.x * 64;
  int tx = tid & 15, ty = tid >> 4;
  float acc[4][4] = {};
  for (int k0 = 0; k0 < K; k0 += 16) {
#pragma unroll
    for (int r = 0; r < 4; ++r) {
      int m = (tid >> 4) + r * 16;
      int k = tid & 15;
      As[k][m] = A[(size_t)(bm + m) * K + k0 + k];
    }
#pragma unroll
    for (int r = 0; r < 4; ++r) {
      int n = tid & 63;
      int k = (tid >> 6) + r * 4;
      int gn = bn + n;
      Bs[k][n] = (gn < N) ? B[(size_t)(k0 + k) * N + gn] : 0.0f;
    }
    __syncthreads();
#pragma unroll
    for (int kk = 0; kk < 16; ++kk) {
      float a[4], bb[4];
#pragma unroll
      for (int i = 0; i < 4; ++i) a[i] = As[kk][ty * 4 + i];
#pragma unroll
      for (int jj = 0; jj < 4; ++jj) bb[jj] = Bs[kk][tx * 4 + jj];
#pragma unroll
      for (int i = 0; i < 4; ++i)
#pragma unroll
        for (int jj = 0; jj < 4; ++jj) acc[i][jj] = fmaf(a[i], bb[jj], acc[i][jj]);
    }
    __syncthreads();
  }
#pragma unroll
  for (int i = 0; i < 4; ++i) {
    int m = bm + ty * 4 + i;
#pragma unroll
    for (int jj = 0; jj < 4; ++jj) {
      int n = bn + tx * 4 + jj;
      if (n < N) {
        float v = acc[i][jj] + bias[n];
        if (act == 1) v = fmaxf(v, 0.0f);
        C[(size_t)m * N + n] = v;
      }
    }
  }
}

// ------------------------- big fp32 GEMM: 128x128 tile, 8x8/thread, grid.z batched -------------------------
struct GemmB {
  const float* A[4];
  const float* B[4];
  const float* bias[4];
  float* C[4];
};

// flags bit0: B-tile rows fully in-bounds & 16B-alignable (vector staging)
// flags bit1: C vector stores allowed (aligned, no N-edge)
__global__ __launch_bounds__(256, 4) void gemm128(
    GemmB gb, int M, int N, int K, int ldb, long long ldc, int act, int flags) {
  const int e = blockIdx.z;
  const float* __restrict__ A = gb.A[e];
  const float* __restrict__ B = gb.B[e];
  const float* __restrict__ bias = gb.bias[e];
  float* __restrict__ C = gb.C[e];
  __shared__ float As[16][128];
  __shared__ float Bs[16][128];
  const int tid = threadIdx.x;
  const int bm = blockIdx.y * 128, bn = blockIdx.x * 128;
  const int tx = tid & 15, ty = tid >> 4;
  // A staging: lane-major in m (2-way LDS bank alias only)
  const int am = tid & 63;            // + 64 second row block
  const int akq = (tid >> 6) * 4;     // k quad: 0,4,8,12
  // B staging: coalesced in n
  const int bkk = tid >> 5;           // 0..7 (+8)
  const int bc4 = (tid & 31) * 4;     // n offset 0..124
  float acc[8][8] = {};
  for (int k0 = 0; k0 < K; k0 += 16) {
    {
      const float4 v0 = *(const float4*)(A + (size_t)(bm + am) * K + k0 + akq);
      const float4 v1 = *(const float4*)(A + (size_t)(bm + am + 64) * K + k0 + akq);
      As[akq + 0][am] = v0.x; As[akq + 1][am] = v0.y;
      As[akq + 2][am] = v0.z; As[akq + 3][am] = v0.w;
      As[akq + 0][am + 64] = v1.x; As[akq + 1][am + 64] = v1.y;
      As[akq + 2][am + 64] = v1.z; As[akq + 3][am + 64] = v1.w;
    }
    if (flags & 1) {
#pragma unroll
      for (int r = 0; r < 2; ++r) {
        const int kz = k0 + bkk + r * 8;
        const float4 v = *(const float4*)(B + (size_t)kz * ldb + bn + bc4);
        *(float4*)&Bs[bkk + r * 8][bc4] = v;
      }
    } else {
#pragma unroll
      for (int r = 0; r < 2; ++r) {
        const int kz = k0 + bkk + r * 8;
        const float* brow = B + (size_t)kz * ldb;
#pragma unroll
        for (int q = 0; q < 4; ++q) {
          const int gn = bn + bc4 + q;
          Bs[bkk + r * 8][bc4 + q] = (gn < N) ? brow[gn] : 0.0f;
        }
      }
    }
    __syncthreads();
#pragma unroll
    for (int kk = 0; kk < 16; ++kk) {
      float a[8], b[8];
      *(float4*)&a[0] = *(const float4*)&As[kk][ty * 4];
      *(float4*)&a[4] = *(const float4*)&As[kk][64 + ty * 4];
      *(float4*)&b[0] = *(const float4*)&Bs[kk][tx * 4];
      *(float4*)&b[4] = *(const float4*)&Bs[kk][64 + tx * 4];
#pragma unroll
      for (int i = 0; i < 8; ++i)
#pragma unroll
        for (int jj = 0; jj < 8; ++jj)
          acc[i][jj] = fmaf(a[i], b[jj], acc[i][jj]);
    }
    __syncthreads();
  }
  if (flags & 2) {
    float bv[8];
#pragma unroll
    for (int jj = 0; jj < 8; ++jj)
      bv[jj] = bias[bn + ((jj < 4) ? (tx * 4 + jj) : (64 + tx * 4 + jj - 4))];
#pragma unroll
    for (int i = 0; i < 8; ++i) {
      const int m = bm + ((i < 4) ? (ty * 4 + i) : (64 + ty * 4 + i - 4));
      float* crow = C + (size_t)m * ldc + bn;
      float4 s0, s1;
      s0.x = acc[i][0] + bv[0]; s0.y = acc[i][1] + bv[1];
      s0.z = acc[i][2] + bv[2]; s0.w = acc[i][3] + bv[3];
      s1.x = acc[i][4] + bv[4]; s1.y = acc[i][5] + bv[5];
      s1.z = acc[i][6] + bv[6]; s1.w = acc[i][7] + bv[7];
      if (act) {
        s0.x = fmaxf(s0.x, 0.f); s0.y = fmaxf(s0.y, 0.f); s0.z = fmaxf(s0.z, 0.f); s0.w = fmaxf(s0.w, 0.f);
        s1.x = fmaxf(s1.x, 0.f); s1.y = fmaxf(s1.y, 0.f); s1.z = fmaxf(s1.z, 0.f); s1.w = fmaxf(s1.w, 0.f);
      }
      *(float4*)(crow + tx * 4) = s0;
      *(float4*)(crow + 64 + tx * 4) = s1;
    }
  } else {
#pragma unroll
    for (int i = 0; i < 8; ++i) {
      const int m = bm + ((i < 4) ? (ty * 4 + i) : (64 + ty * 4 + i - 4));
#pragma unroll
      for (int jj = 0; jj < 8; ++jj) {
        const int n = bn + ((jj < 4) ? (tx * 4 + jj) : (64 + tx * 4 + jj - 4));
        if (n < N) {
          float v = acc[i][jj] + bias[n];
          if (act) v = fmaxf(v, 0.0f);
          C[(size_t)m * ldc + n] = v;
        }
      }
    }
  }
}

// ------------------------- init per-head state: h=0, curin=cls -------------------------
__global__ __launch_bounds__(256) void init_state_kernel(
    const float* __restrict__ cls, float* __restrict__ h2, float* __restrict__ cur2) {
  int idx = blockIdx.x * blockDim.x + threadIdx.x;
  if (idx >= 2 * BH) return;
  int rem = idx % BH;
  h2[idx] = 0.0f;
  cur2[idx] = cls[rem];
}

// ------------------------- GRU gate combine (both heads) -------------------------
__global__ __launch_bounds__(256) void gru_combine_kernel(
    const float* __restrict__ gi2, const float* __restrict__ gh2, float* __restrict__ h2) {
  int idx = blockIdx.x * blockDim.x + threadIdx.x;
  if (idx >= 2 * BH) return;
  int e = idx / BH, rem = idx % BH;
  int b = rem / H_DIM, c = rem - b * H_DIM;
  const float* gib = gi2 + ((size_t)e * B_DIM + b) * 3 * H_DIM;
  const float* ghb = gh2 + ((size_t)e * B_DIM + b) * 3 * H_DIM;
  float ir = gib[c], iz = gib[H_DIM + c], inn = gib[2 * H_DIM + c];
  float hr = ghb[c], hz = ghb[H_DIM + c], hn = ghb[2 * H_DIM + c];
  float r = sigmoidf_(ir + hr);
  float z = sigmoidf_(iz + hz);
  float n = tanhf(inn + r * hn);
  h2[idx] = (1.0f - z) * n + z * h2[idx];
}

// ------------------------- cur_in = cls + ae_w[ind] (both heads) -------------------------
__global__ __launch_bounds__(256) void curin_kernel(
    const float* __restrict__ cls, const float* __restrict__ ae_w,
    const int* __restrict__ indb, int j, float* __restrict__ cur2) {
  int idx = blockIdx.x * blockDim.x + threadIdx.x;
  if (idx >= 2 * BH) return;
  int e = idx / BH, rem = idx % BH;
  int b = rem / H_DIM, c = rem - b * H_DIM;
  int ind = indb[(e * NSTEPS + j) * B_DIM + b];
  cur2[idx] = cls[rem] + ae_w[(size_t)ind * H_DIM + c];
}

// ------------------------- sampling (both heads), in-place on probs rows -------------------------
#define STH 256
#define PER_TH 20  // ceil(5001/256)

__global__ __launch_bounds__(STH) void sample_kernel(
    float* __restrict__ probs, const int* __restrict__ x_mask,
    int* __restrict__ indb, int j, uint4 keys) {
  int b = blockIdx.x;
  int e = blockIdx.y;
  int t = threadIdx.x;
  uint32_t k0 = (e == 0) ? keys.x : keys.z;
  uint32_t k1 = (e == 0) ? keys.y : keys.w;
  __shared__ float rv[STH];
  __shared__ int ri[STH];
  __shared__ int s_ind;

  float* prow = probs + (((size_t)b * NHEADS + e) * NSTEPS + j) * A_DIM;  // logits in, one-hot out
  const int* mrow = x_mask + (size_t)b * A_DIM;

  int prev[3];
  bool dead = false;
  for (int tt = 0; tt < j; ++tt) {
    prev[tt] = indb[(e * NSTEPS + tt) * B_DIM + b];
    if (prev[tt] == 0) dead = true;
  }

  bool rowany = true;
  if (j == 0) {
    int any = 0;
    for (int a = t; a < A_DIM; a += STH) any |= mrow[a];
    ri[t] = any; __syncthreads();
    for (int s = STH / 2; s > 0; s >>= 1) {
      if (t < s) ri[t] |= ri[t + s];
      __syncthreads();
    }
    rowany = (ri[0] != 0);
    __syncthreads();
  }

  float v[PER_TH];
  float lmax = -3.0e38f;
#pragma unroll
  for (int s = 0; s < PER_TH; ++s) {
    int a = t + s * STH;
    float val = -3.0e38f;
    if (a < A_DIM) {
      int m;
      if (j == 0) {
        m = (a == 0) ? (rowany ? mrow[0] : 1) : mrow[a];
      } else if (a == 0) {
        m = 1;
      } else if (dead) {
        m = 0;
      } else {
        m = mrow[a];
        if (m) {
          for (int tt = 0; tt < j; ++tt)
            if (prev[tt] == a) { m = 0; break; }
        }
      }
      if (m > 0)  // masked entries: exp underflows to exact 0 either way; skip gumbel
        val = prow[a] + gumbel_noise(k0, k1, (uint32_t)(b * A_DIM + a));
    }
    v[s] = val;
    lmax = fmaxf(lmax, val);
  }

  rv[t] = lmax; __syncthreads();
  for (int s = STH / 2; s > 0; s >>= 1) {
    if (t < s) rv[t] = fmaxf(rv[t], rv[t + s]);
    __syncthreads();
  }
  float m = rv[0]; __syncthreads();

  float lsum = 0.0f;
#pragma unroll
  for (int s = 0; s < PER_TH; ++s) {
    int a = t + s * STH;
    float ev = (a < A_DIM && v[s] > -1.0e37f) ? expf(v[s] - m) : 0.0f;
    v[s] = ev; lsum += ev;
  }
  rv[t] = lsum; __syncthreads();
  for (int s = STH / 2; s > 0; s >>= 1) {
    if (t < s) rv[t] += rv[t + s];
    __syncthreads();
  }
  float ssum = rv[0]; __syncthreads();

  float besty = -1.0f; int besti = A_DIM;
#pragma unroll
  for (int s = 0; s < PER_TH; ++s) {
    int a = t + s * STH;
    if (a < A_DIM) {
      float y = v[s] / ssum;
      if (y > besty) { besty = y; besti = a; }
    }
  }
  rv[t] = besty; ri[t] = besti; __syncthreads();
  for (int s = STH / 2; s > 0; s >>= 1) {
    if (t < s) {
      float y2 = rv[t + s]; int i2 = ri[t + s];
      if (y2 > rv[t] || (y2 == rv[t] && i2 < ri[t])) { rv[t] = y2; ri[t] = i2; }
    }
    __syncthreads();
  }
  if (t == 0) { s_ind = ri[0]; indb[(e * NSTEPS + j) * B_DIM + b] = ri[0]; }
  __syncthreads();
  int ind = s_ind;

  for (int a = t; a < A_DIM; a += STH) prow[a] = (a == ind) ? 1.0f : 0.0f;
}

// ------------------------- per-head consequent estimator (both heads) -------------------------
__global__ __launch_bounds__(256) void head_final_kernel(
    const int* __restrict__ indb, const float* __restrict__ Wmu,
    const float* __restrict__ bmu, const float* __restrict__ Wcov,
    const float* __restrict__ bcov, const float* __restrict__ alpha,
    float* __restrict__ matcp) {
  int idx = blockIdx.x * blockDim.x + threadIdx.x;
  if (idx >= NHEADS * B_DIM) return;
  int e = idx / B_DIM, b = idx - e * B_DIM;
  float a0 = 0.0f, a1 = 0.0f, ac = 0.0f;
  for (int j = 0; j < NSTEPS; ++j) {
    int ind = indb[(e * NSTEPS + j) * B_DIM + b];
    a0 += 0.25f * Wmu[(size_t)ind * C_DIM + 0];
    a1 += 0.25f * Wmu[(size_t)ind * C_DIM + 1];
    ac += 0.25f * Wcov[ind];
  }
  float mu0 = sigmoidf_(a0 + bmu[0]);
  float mu1 = sigmoidf_(a1 + bmu[1]);
  float cov = sigmoidf_(ac + bcov[0]);
  float n = cov * 56000.0f;
  float sf = alpha[0] / n;
  float denom = 1.0f + 2.0f * sf;
  matcp[((size_t)b * NHEADS + e) * C_DIM + 0] = (mu0 + sf) / denom;
  matcp[((size_t)b * NHEADS + e) * C_DIM + 1] = (mu1 + sf) / denom;
}

__global__ __launch_bounds__(256) void final_out_kernel(
    const float* __restrict__ matcp, float* __restrict__ out) {
  int idx = blockIdx.x * blockDim.x + threadIdx.x;
  if (idx >= B_DIM * C_DIM) return;
  int b = idx / C_DIM, c = idx - b * C_DIM;
  float s = matcp[((size_t)b * NHEADS + 0) * C_DIM + c] +
            matcp[((size_t)b * NHEADS + 1) * C_DIM + c];
  out[idx] = logf(s * 0.5f);
}

// ------------------------- orchestration -------------------------
extern "C" void kernel_launch(void* const* d_in, const int* in_sizes, int n_in,
                              void* d_out, int out_size, void* d_ws, size_t ws_size,
                              hipStream_t stream) {
  const float* x     = (const float*)d_in[0];
  const int*   xmask = (const int*)d_in[1];
  const float* W1 = (const float*)d_in[2];  const float* b1 = (const float*)d_in[3];
  const float* W2 = (const float*)d_in[4];  const float* b2 = (const float*)d_in[5];
  const float* W3 = (const float*)d_in[6];  const float* b3 = (const float*)d_in[7];
  const float* gWih = (const float*)d_in[8];  const float* gWhh = (const float*)d_in[9];
  const float* gbih = (const float*)d_in[10]; const float* gbhh = (const float*)d_in[11];
  const float* hW = (const float*)d_in[12];   const float* hb = (const float*)d_in[13];
  const float* ae_w = (const float*)d_in[14];
  const float* Wmu  = (const float*)d_in[15]; const float* bmu  = (const float*)d_in[16];
  const float* Wcov = (const float*)d_in[17]; const float* bcov = (const float*)d_in[18];
  const float* alpha = (const float*)d_in[19];

  float* out = (float*)d_out;
  float* probs = out + (size_t)B_DIM * C_DIM;                       // [B, 2, 4, A]
  float* matcp = probs + (size_t)B_DIM * NHEADS * NSTEPS * A_DIM;   // [B, 2, C]

  float* cls  = (float*)d_ws;          // BH
  float* h2   = cls + BH;              // 2*BH
  float* cur2 = h2 + 2 * (size_t)BH;   // 2*BH
  float* gi2  = cur2 + 2 * (size_t)BH; // 6*BH
  float* gh2  = gi2 + 6 * (size_t)BH;  // 6*BH
  int*   indb = (int*)(gh2 + 6 * (size_t)BH);  // 2*4*B ints
  float* t1 = gi2;                     // MLP temps (gi2 free pre-loop)
  float* t2 = gi2 + BH;

  dim3 blk(256);
  auto gemm64 = [&](const float* Am, const float* Bm, const float* bias, float* Cm,
                    int M, int N, int K, int act) {
    dim3 grid((N + 63) / 64, M / 64);
    gemm_bias_act<<<grid, blk, 0, stream>>>(Am, Bm, bias, Cm, M, N, K, act);
  };

  // MLP: cls = (relu(relu(x@W1+b1)@W2+b2))@W3 + b3
  gemm64(x, W1, b1, t1, B_DIM, H_DIM, DIN, 1);
  gemm64(t1, W2, b2, t2, B_DIM, H_DIM, H_DIM, 1);
  gemm64(t2, W3, b3, cls, B_DIM, H_DIM, H_DIM, 0);

  init_state_kernel<<<(2 * BH + 255) / 256, blk, 0, stream>>>(cls, h2, cur2);

  // host-side key schedule: key(42) -> fold_in(head) -> fold_in(step)
  uint32_t bk0 = 0u, bk1 = 42u;
  uint32_t hk[2][2];
  threefry2x32(bk0, bk1, 0u, 0u, hk[0][0], hk[0][1]);
  threefry2x32(bk0, bk1, 0u, 1u, hk[1][0], hk[1][1]);

  const int HG = 3 * H_DIM;  // 2304
  for (int j = 0; j < NSTEPS; ++j) {
    // gates: z=4 -> {h0:gi, h0:gh, h1:gi, h1:gh}
    GemmB gb;
    for (int head = 0; head < NHEADS; ++head) {
      gb.A[head * 2 + 0] = cur2 + (size_t)head * BH;
      gb.B[head * 2 + 0] = gWih + (size_t)head * H_DIM * HG;
      gb.bias[head * 2 + 0] = gbih + (size_t)head * HG;
      gb.C[head * 2 + 0] = gi2 + (size_t)head * B_DIM * HG;
      gb.A[head * 2 + 1] = h2 + (size_t)head * BH;
      gb.B[head * 2 + 1] = gWhh + (size_t)head * H_DIM * HG;
      gb.bias[head * 2 + 1] = gbhh + (size_t)head * HG;
      gb.C[head * 2 + 1] = gh2 + (size_t)head * B_DIM * HG;
    }
    gemm128<<<dim3(HG / 128, B_DIM / 128, 4), blk, 0, stream>>>(
        gb, B_DIM, HG, H_DIM, HG, (long long)HG, 0, 3);

    gru_combine_kernel<<<(2 * BH + 255) / 256, blk, 0, stream>>>(gi2, gh2, h2);

    // logits: z=2, write into probs rows (scratch; sampler overwrites in place)
    GemmB lb;
    for (int head = 0; head < NHEADS; ++head) {
      lb.A[head] = h2 + (size_t)head * BH;
      lb.B[head] = hW + (size_t)head * H_DIM * A_DIM;
      lb.bias[head] = hb + (size_t)head * A_DIM;
      lb.C[head] = probs + (size_t)(head * NSTEPS + j) * A_DIM;
    }
    gemm128<<<dim3((A_DIM + 127) / 128, B_DIM / 128, 2), blk, 0, stream>>>(
        lb, B_DIM, A_DIM, H_DIM, A_DIM, (long long)(NHEADS * NSTEPS * A_DIM), 0, 0);

    uint32_t s00, s01, s10, s11;
    threefry2x32(hk[0][0], hk[0][1], 0u, (uint32_t)j, s00, s01);
    threefry2x32(hk[1][0], hk[1][1], 0u, (uint32_t)j, s10, s11);
    uint4 keys; keys.x = s00; keys.y = s01; keys.z = s10; keys.w = s11;
    sample_kernel<<<dim3(B_DIM, NHEADS), dim3(STH), 0, stream>>>(probs, xmask, indb, j, keys);

    if (j < NSTEPS - 1)
      curin_kernel<<<(2 * BH + 255) / 256, blk, 0, stream>>>(cls, ae_w, indb, j, cur2);
  }

  head_final_kernel<<<(NHEADS * B_DIM + 255) / 256, blk, 0, stream>>>(
      indb, Wmu, bmu, Wcov, bcov, alpha, matcp);
  final_out_kernel<<<(B_DIM * C_DIM + 255) / 256, blk, 0, stream>>>(matcp, out);
}

// Round 3
// 2210.724 us; speedup vs baseline: 1.3680x; 1.0701x over previous
//
#include <hip/hip_runtime.h>
#include <hip/hip_bf16.h>
#include <stdint.h>
#include <stddef.h>

#define B_DIM   1024
#define DIN     512
#define H_DIM   768
#define A_DIM   5001
#define NHEADS  2
#define NSTEPS  4
#define C_DIM   2
#define NEG_VAL -1e30f
#define BH      (B_DIM * H_DIM)

typedef unsigned short u16;
typedef __attribute__((ext_vector_type(8))) short v8s;
typedef __attribute__((ext_vector_type(4))) float v4f;

// ------------------------- Threefry-2x32 (JAX-compatible) -------------------------
__host__ __device__ inline uint32_t rotl32(uint32_t x, int d) {
  return (x << d) | (x >> (32 - d));
}

__host__ __device__ inline void threefry2x32(uint32_t k0, uint32_t k1,
                                             uint32_t x0, uint32_t x1,
                                             uint32_t& o0, uint32_t& o1) {
  uint32_t ks2 = k0 ^ k1 ^ 0x1BD11BDAu;
  x0 += k0; x1 += k1;
#define TFR(d) { x0 += x1; x1 = rotl32(x1, (d)); x1 ^= x0; }
  TFR(13) TFR(15) TFR(26) TFR(6)  x0 += k1;  x1 += ks2 + 1u;
  TFR(17) TFR(29) TFR(16) TFR(24) x0 += ks2; x1 += k0 + 2u;
  TFR(13) TFR(15) TFR(26) TFR(6)  x0 += k0;  x1 += k1 + 3u;
  TFR(17) TFR(29) TFR(16) TFR(24) x0 += k1;  x1 += ks2 + 4u;
  TFR(13) TFR(15) TFR(26) TFR(6)  x0 += ks2; x1 += k0 + 5u;
#undef TFR
  o0 = x0; o1 = x1;
}

__device__ inline float gumbel_noise(uint32_t k0, uint32_t k1, uint32_t idx) {
  uint32_t o0, o1;
  threefry2x32(k0, k1, 0u, idx, o0, o1);
  uint32_t bits = o0 ^ o1;
  float f = __uint_as_float(0x3f800000u | (bits >> 9)) - 1.0f;   // [0,1)
  float u = fmaxf(1e-9f, f * (1.0f - 1e-9f) + 1e-9f);            // jax.random.uniform
  return -logf(-logf(u));                                        // Gumbel(0,1)
}

// XLA logistic lowering: 0.5 + 0.5 * tanh(0.5 * x)
__device__ inline float sigmoidf_(float x) { return 0.5f * tanhf(0.5f * x) + 0.5f; }

__device__ inline void split_bf16(float x, u16& hi, u16& lo) {
  __hip_bfloat16 h = __float2bfloat16(x);
  float hf = __bfloat162float(h);
  __hip_bfloat16 l = __float2bfloat16(x - hf);
  hi = *(const u16*)&h;
  lo = *(const u16*)&l;
}

// ------------------------- small fp32 GEMM (MLP): 64x64 tile, 4x4/thread -------------------------
__global__ __launch_bounds__(256) void gemm_bias_act(
    const float* __restrict__ A, const float* __restrict__ B,
    const float* __restrict__ bias, float* __restrict__ C,
    int M, int N, int K, int act) {
  __shared__ float As[16][65];
  __shared__ float Bs[16][64];
  int tid = threadIdx.x;
  int bm = blockIdx.y * 64, bn = blockIdx.x * 64;
  int tx = tid & 15, ty = tid >> 4;
  float acc[4][4] = {};
  for (int k0 = 0; k0 < K; k0 += 16) {
#pragma unroll
    for (int r = 0; r < 4; ++r) {
      int m = (tid >> 4) + r * 16;
      int k = tid & 15;
      As[k][m] = A[(size_t)(bm + m) * K + k0 + k];
    }
#pragma unroll
    for (int r = 0; r < 4; ++r) {
      int n = tid & 63;
      int k = (tid >> 6) + r * 4;
      int gn = bn + n;
      Bs[k][n] = (gn < N) ? B[(size_t)(k0 + k) * N + gn] : 0.0f;
    }
    __syncthreads();
#pragma unroll
    for (int kk = 0; kk < 16; ++kk) {
      float a[4], bb[4];
#pragma unroll
      for (int i = 0; i < 4; ++i) a[i] = As[kk][ty * 4 + i];
#pragma unroll
      for (int jj = 0; jj < 4; ++jj) bb[jj] = Bs[kk][tx * 4 + jj];
#pragma unroll
      for (int i = 0; i < 4; ++i)
#pragma unroll
        for (int jj = 0; jj < 4; ++jj) acc[i][jj] = fmaf(a[i], bb[jj], acc[i][jj]);
    }
    __syncthreads();
  }
#pragma unroll
  for (int i = 0; i < 4; ++i) {
    int m = bm + ty * 4 + i;
#pragma unroll
    for (int jj = 0; jj < 4; ++jj) {
      int n = bn + tx * 4 + jj;
      if (n < N) {
        float v = acc[i][jj] + bias[n];
        if (act == 1) v = fmaxf(v, 0.0f);
        C[(size_t)m * N + n] = v;
      }
    }
  }
}

// ------------------------- weight transpose + bf16 split: W[K][N] -> hi/lo[N][K] -------------------------
__global__ __launch_bounds__(256) void transpose_split(
    const float* __restrict__ W, u16* __restrict__ hi, u16* __restrict__ lo,
    int K, int N, size_t inStride, size_t outStride) {
  const int e = blockIdx.z;
  const float* Win = W + (size_t)e * inStride;
  u16* ho = hi + (size_t)e * outStride;
  u16* loo = lo + (size_t)e * outStride;
  __shared__ float tile[32][33];
  const int k0 = blockIdx.y * 32, n0 = blockIdx.x * 32;
  const int tx = threadIdx.x & 31, ty = threadIdx.x >> 5;
#pragma unroll
  for (int r = ty; r < 32; r += 8) {
    int n = n0 + tx;
    tile[r][tx] = (n < N) ? Win[(size_t)(k0 + r) * N + n] : 0.0f;
  }
  __syncthreads();
#pragma unroll
  for (int r = ty; r < 32; r += 8) {
    int n = n0 + r, k = k0 + tx;
    if (n < N) {
      u16 h, l;
      split_bf16(tile[tx][r], h, l);
      ho[(size_t)n * K + k] = h;
      loo[(size_t)n * K + k] = l;
    }
  }
}

// ------------------------- bf16x3 MFMA GEMM: 128x128 tile, 4 waves, BK=32 -------------------------
struct GemmS {
  const u16* Ah[4]; const u16* Al[4];
  const u16* Bh[4]; const u16* Bl[4];
  const float* bias[4]; float* C[4];
};

__global__ __launch_bounds__(256, 2) void gemm_mfma(
    GemmS gs, int K, int N, int Nclamp, long long ldc, int nbx, int nby) {
  const int e = blockIdx.y;
  // XCD-chunked, m-fastest block ordering (nbx*nby divisible by 8)
  const int nwg = nbx * nby;
  const int chunk = nwg >> 3;
  const int orig = blockIdx.x;
  const int lid = (orig & 7) * chunk + (orig >> 3);
  const int by = lid % nby;
  const int bx = lid / nby;
  const int bm = by * 128, bn = bx * 128;

  __shared__ __align__(16) u16 lds[4][128 * 32];  // Ahi, Alo, Bhi, Blo (8KB each)

  const int tid = threadIdx.x;
  const int wv = tid >> 6, ln = tid & 63;
  const int wr = wv >> 1, wc = wv & 1;     // wave 2x2 grid
  const int lk = ln >> 4;                  // k-group 0..3
  const int lm = ln & 15;                  // frag row/col
  const int fswz = (lm >> 1) & 3;          // read-side XOR swizzle

  const int srow = tid >> 1;               // staging row 0..127
  const int s0 = (tid & 1) * 2;            // staging slot base
  const int sswz = (srow >> 1) & 3;        // store-side XOR swizzle

  const u16* Ah = gs.Ah[e]; const u16* Al = gs.Al[e];
  const u16* Bh = gs.Bh[e]; const u16* Bl = gs.Bl[e];
  const float* bias = gs.bias[e];
  float* C = gs.C[e];

  const size_t arow = (size_t)(bm + srow) * K;
  const int bri = bn + srow;
  const size_t brow = (size_t)((bri < Nclamp) ? bri : (Nclamp - 1)) * K;

  v4f acc[4][4];
#pragma unroll
  for (int i = 0; i < 4; ++i)
#pragma unroll
    for (int j = 0; j < 4; ++j) acc[i][j] = (v4f){0.f, 0.f, 0.f, 0.f};

  uint4 st[4][2];
#define DO_LOADS(k0)                                              \
  {                                                               \
    _Pragma("unroll")                                             \
    for (int q = 0; q < 2; ++q) {                                 \
      const int g = (s0 + q) ^ sswz;                              \
      st[0][q] = *(const uint4*)(Ah + arow + (k0) + g * 8);       \
      st[1][q] = *(const uint4*)(Al + arow + (k0) + g * 8);       \
      st[2][q] = *(const uint4*)(Bh + brow + (k0) + g * 8);       \
      st[3][q] = *(const uint4*)(Bl + brow + (k0) + g * 8);       \
    }                                                             \
  }

  DO_LOADS(0)
  for (int k0 = 0; k0 < K; k0 += 32) {
    __syncthreads();
#pragma unroll
    for (int t = 0; t < 4; ++t)
#pragma unroll
      for (int q = 0; q < 2; ++q)
        *(uint4*)&lds[t][srow * 32 + (s0 + q) * 8] = st[t][q];
    __syncthreads();
    if (k0 + 32 < K) DO_LOADS(k0 + 32)

    v8s ah[4], al[4], bh[4], bl[4];
#pragma unroll
    for (int mi = 0; mi < 4; ++mi) {
      const int r = wr * 64 + mi * 16 + lm;
      const int off = r * 32 + ((lk ^ fswz) * 8);
      ah[mi] = *(const v8s*)&lds[0][off];
      al[mi] = *(const v8s*)&lds[1][off];
    }
#pragma unroll
    for (int ni = 0; ni < 4; ++ni) {
      const int r = wc * 64 + ni * 16 + lm;
      const int off = r * 32 + ((lk ^ fswz) * 8);
      bh[ni] = *(const v8s*)&lds[2][off];
      bl[ni] = *(const v8s*)&lds[3][off];
    }
    // 3-term split product, 16-MFMA spacing between same-acc uses
#pragma unroll
    for (int mi = 0; mi < 4; ++mi)
#pragma unroll
      for (int ni = 0; ni < 4; ++ni)
        acc[mi][ni] = __builtin_amdgcn_mfma_f32_16x16x32_bf16(ah[mi], bh[ni], acc[mi][ni], 0, 0, 0);
#pragma unroll
    for (int mi = 0; mi < 4; ++mi)
#pragma unroll
      for (int ni = 0; ni < 4; ++ni)
        acc[mi][ni] = __builtin_amdgcn_mfma_f32_16x16x32_bf16(ah[mi], bl[ni], acc[mi][ni], 0, 0, 0);
#pragma unroll
    for (int mi = 0; mi < 4; ++mi)
#pragma unroll
      for (int ni = 0; ni < 4; ++ni)
        acc[mi][ni] = __builtin_amdgcn_mfma_f32_16x16x32_bf16(al[mi], bh[ni], acc[mi][ni], 0, 0, 0);
  }

  // epilogue: C/D layout col=lane&15, row=(lane>>4)*4+reg (m89-verified)
#pragma unroll
  for (int mi = 0; mi < 4; ++mi) {
    const int m = bm + wr * 64 + mi * 16 + lk * 4;
#pragma unroll
    for (int ni = 0; ni < 4; ++ni) {
      const int n = bn + wc * 64 + ni * 16 + lm;
      if (n < N) {
        const float bv = bias[n];
        float* cp = C + (size_t)m * ldc + n;
#pragma unroll
        for (int r = 0; r < 4; ++r)
          cp[(size_t)r * ldc] = acc[mi][ni][r] + bv;
      }
    }
  }
}

// ------------------------- init per-head state: h=0 (+split), cur=cls (+split) -------------------------
__global__ __launch_bounds__(256) void init_state_kernel(
    const float* __restrict__ cls, float* __restrict__ h2,
    u16* __restrict__ h_hi, u16* __restrict__ h_lo,
    u16* __restrict__ cur_hi, u16* __restrict__ cur_lo) {
  int idx = blockIdx.x * blockDim.x + threadIdx.x;
  if (idx >= 2 * BH) return;
  int rem = idx % BH;
  h2[idx] = 0.0f;
  h_hi[idx] = 0; h_lo[idx] = 0;
  u16 h, l;
  split_bf16(cls[rem], h, l);
  cur_hi[idx] = h; cur_lo[idx] = l;
}

// ------------------------- GRU gate combine (both heads) + h split -------------------------
__global__ __launch_bounds__(256) void gru_combine_kernel(
    const float* __restrict__ gi2, const float* __restrict__ gh2, float* __restrict__ h2,
    u16* __restrict__ h_hi, u16* __restrict__ h_lo) {
  int idx = blockIdx.x * blockDim.x + threadIdx.x;
  if (idx >= 2 * BH) return;
  int e = idx / BH, rem = idx % BH;
  int b = rem / H_DIM, c = rem - b * H_DIM;
  const float* gib = gi2 + ((size_t)e * B_DIM + b) * 3 * H_DIM;
  const float* ghb = gh2 + ((size_t)e * B_DIM + b) * 3 * H_DIM;
  float ir = gib[c], iz = gib[H_DIM + c], inn = gib[2 * H_DIM + c];
  float hr = ghb[c], hz = ghb[H_DIM + c], hn = ghb[2 * H_DIM + c];
  float r = sigmoidf_(ir + hr);
  float z = sigmoidf_(iz + hz);
  float n = tanhf(inn + r * hn);
  float hv = (1.0f - z) * n + z * h2[idx];
  h2[idx] = hv;
  u16 h, l;
  split_bf16(hv, h, l);
  h_hi[idx] = h; h_lo[idx] = l;
}

// ------------------------- cur_in = cls + ae_w[ind] (both heads), split output -------------------------
__global__ __launch_bounds__(256) void curin_kernel(
    const float* __restrict__ cls, const float* __restrict__ ae_w,
    const int* __restrict__ indb, int j,
    u16* __restrict__ cur_hi, u16* __restrict__ cur_lo) {
  int idx = blockIdx.x * blockDim.x + threadIdx.x;
  if (idx >= 2 * BH) return;
  int e = idx / BH, rem = idx % BH;
  int b = rem / H_DIM, c = rem - b * H_DIM;
  int ind = indb[(e * NSTEPS + j) * B_DIM + b];
  float v = cls[rem] + ae_w[(size_t)ind * H_DIM + c];
  u16 h, l;
  split_bf16(v, h, l);
  cur_hi[idx] = h; cur_lo[idx] = l;
}

// ------------------------- sampling (both heads), in-place on probs rows -------------------------
#define STH 256
#define PER_TH 20  // ceil(5001/256)

__global__ __launch_bounds__(STH) void sample_kernel(
    float* __restrict__ probs, const int* __restrict__ x_mask,
    int* __restrict__ indb, int j, uint4 keys) {
  int b = blockIdx.x;
  int e = blockIdx.y;
  int t = threadIdx.x;
  uint32_t k0 = (e == 0) ? keys.x : keys.z;
  uint32_t k1 = (e == 0) ? keys.y : keys.w;
  __shared__ float rv[STH];
  __shared__ int ri[STH];
  __shared__ int s_ind;

  float* prow = probs + (((size_t)b * NHEADS + e) * NSTEPS + j) * A_DIM;
  const int* mrow = x_mask + (size_t)b * A_DIM;

  int prev[3];
  bool dead = false;
  for (int tt = 0; tt < j; ++tt) {
    prev[tt] = indb[(e * NSTEPS + tt) * B_DIM + b];
    if (prev[tt] == 0) dead = true;
  }

  bool rowany = true;
  if (j == 0) {
    int any = 0;
    for (int a = t; a < A_DIM; a += STH) any |= mrow[a];
    ri[t] = any; __syncthreads();
    for (int s = STH / 2; s > 0; s >>= 1) {
      if (t < s) ri[t] |= ri[t + s];
      __syncthreads();
    }
    rowany = (ri[0] != 0);
    __syncthreads();
  }

  float v[PER_TH];
  float lmax = -3.0e38f;
#pragma unroll
  for (int s = 0; s < PER_TH; ++s) {
    int a = t + s * STH;
    float val = -3.0e38f;
    if (a < A_DIM) {
      int m;
      if (j == 0) {
        m = (a == 0) ? (rowany ? mrow[0] : 1) : mrow[a];
      } else if (a == 0) {
        m = 1;
      } else if (dead) {
        m = 0;
      } else {
        m = mrow[a];
        if (m) {
          for (int tt = 0; tt < j; ++tt)
            if (prev[tt] == a) { m = 0; break; }
        }
      }
      if (m > 0)
        val = prow[a] + gumbel_noise(k0, k1, (uint32_t)(b * A_DIM + a));
    }
    v[s] = val;
    lmax = fmaxf(lmax, val);
  }

  rv[t] = lmax; __syncthreads();
  for (int s = STH / 2; s > 0; s >>= 1) {
    if (t < s) rv[t] = fmaxf(rv[t], rv[t + s]);
    __syncthreads();
  }
  float m = rv[0]; __syncthreads();

  float lsum = 0.0f;
#pragma unroll
  for (int s = 0; s < PER_TH; ++s) {
    int a = t + s * STH;
    float ev = (a < A_DIM && v[s] > -1.0e37f) ? expf(v[s] - m) : 0.0f;
    v[s] = ev; lsum += ev;
  }
  rv[t] = lsum; __syncthreads();
  for (int s = STH / 2; s > 0; s >>= 1) {
    if (t < s) rv[t] += rv[t + s];
    __syncthreads();
  }
  float ssum = rv[0]; __syncthreads();

  float besty = -1.0f; int besti = A_DIM;
#pragma unroll
  for (int s = 0; s < PER_TH; ++s) {
    int a = t + s * STH;
    if (a < A_DIM) {
      float y = v[s] / ssum;
      if (y > besty) { besty = y; besti = a; }
    }
  }
  rv[t] = besty; ri[t] = besti; __syncthreads();
  for (int s = STH / 2; s > 0; s >>= 1) {
    if (t < s) {
      float y2 = rv[t + s]; int i2 = ri[t + s];
      if (y2 > rv[t] || (y2 == rv[t] && i2 < ri[t])) { rv[t] = y2; ri[t] = i2; }
    }
    __syncthreads();
  }
  if (t == 0) { s_ind = ri[0]; indb[(e * NSTEPS + j) * B_DIM + b] = ri[0]; }
  __syncthreads();
  int ind = s_ind;

  for (int a = t; a < A_DIM; a += STH) prow[a] = (a == ind) ? 1.0f : 0.0f;
}

// ------------------------- per-head consequent estimator (both heads) -------------------------
__global__ __launch_bounds__(256) void head_final_kernel(
    const int* __restrict__ indb, const float* __restrict__ Wmu,
    const float* __restrict__ bmu, const float* __restrict__ Wcov,
    const float* __restrict__ bcov, const float* __restrict__ alpha,
    float* __restrict__ matcp) {
  int idx = blockIdx.x * blockDim.x + threadIdx.x;
  if (idx >= NHEADS * B_DIM) return;
  int e = idx / B_DIM, b = idx - e * B_DIM;
  float a0 = 0.0f, a1 = 0.0f, ac = 0.0f;
  for (int j = 0; j < NSTEPS; ++j) {
    int ind = indb[(e * NSTEPS + j) * B_DIM + b];
    a0 += 0.25f * Wmu[(size_t)ind * C_DIM + 0];
    a1 += 0.25f * Wmu[(size_t)ind * C_DIM + 1];
    ac += 0.25f * Wcov[ind];
  }
  float mu0 = sigmoidf_(a0 + bmu[0]);
  float mu1 = sigmoidf_(a1 + bmu[1]);
  float cov = sigmoidf_(ac + bcov[0]);
  float n = cov * 56000.0f;
  float sf = alpha[0] / n;
  float denom = 1.0f + 2.0f * sf;
  matcp[((size_t)b * NHEADS + e) * C_DIM + 0] = (mu0 + sf) / denom;
  matcp[((size_t)b * NHEADS + e) * C_DIM + 1] = (mu1 + sf) / denom;
}

__global__ __launch_bounds__(256) void final_out_kernel(
    const float* __restrict__ matcp, float* __restrict__ out) {
  int idx = blockIdx.x * blockDim.x + threadIdx.x;
  if (idx >= B_DIM * C_DIM) return;
  int b = idx / C_DIM, c = idx - b * C_DIM;
  float s = matcp[((size_t)b * NHEADS + 0) * C_DIM + c] +
            matcp[((size_t)b * NHEADS + 1) * C_DIM + c];
  out[idx] = logf(s * 0.5f);
}

// ------------------------- orchestration -------------------------
extern "C" void kernel_launch(void* const* d_in, const int* in_sizes, int n_in,
                              void* d_out, int out_size, void* d_ws, size_t ws_size,
                              hipStream_t stream) {
  const float* x     = (const float*)d_in[0];
  const int*   xmask = (const int*)d_in[1];
  const float* W1 = (const float*)d_in[2];  const float* b1 = (const float*)d_in[3];
  const float* W2 = (const float*)d_in[4];  const float* b2 = (const float*)d_in[5];
  const float* W3 = (const float*)d_in[6];  const float* b3 = (const float*)d_in[7];
  const float* gWih = (const float*)d_in[8];  const float* gWhh = (const float*)d_in[9];
  const float* gbih = (const float*)d_in[10]; const float* gbhh = (const float*)d_in[11];
  const float* hW = (const float*)d_in[12];   const float* hb = (const float*)d_in[13];
  const float* ae_w = (const float*)d_in[14];
  const float* Wmu  = (const float*)d_in[15]; const float* bmu  = (const float*)d_in[16];
  const float* Wcov = (const float*)d_in[17]; const float* bcov = (const float*)d_in[18];
  const float* alpha = (const float*)d_in[19];

  float* out = (float*)d_out;
  float* probs = out + (size_t)B_DIM * C_DIM;                       // [B, 2, 4, A]
  float* matcp = probs + (size_t)B_DIM * NHEADS * NSTEPS * A_DIM;   // [B, 2, C]

  const int HG = 3 * H_DIM;   // 2304
  uint8_t* wsp = (uint8_t*)d_ws;
  auto alloc = [&](size_t bytes) {
    uint8_t* p = wsp;
    wsp += (bytes + 255) & ~(size_t)255;
    return p;
  };
  float* cls  = (float*)alloc((size_t)BH * 4);
  float* h2   = (float*)alloc((size_t)2 * BH * 4);
  float* gi2  = (float*)alloc((size_t)2 * B_DIM * HG * 4);
  float* gh2  = (float*)alloc((size_t)2 * B_DIM * HG * 4);
  u16* h_hi   = (u16*)alloc((size_t)2 * BH * 2);
  u16* h_lo   = (u16*)alloc((size_t)2 * BH * 2);
  u16* cur_hi = (u16*)alloc((size_t)2 * BH * 2);
  u16* cur_lo = (u16*)alloc((size_t)2 * BH * 2);
  u16* WihT_h = (u16*)alloc((size_t)2 * HG * H_DIM * 2);
  u16* WihT_l = (u16*)alloc((size_t)2 * HG * H_DIM * 2);
  u16* WhhT_h = (u16*)alloc((size_t)2 * HG * H_DIM * 2);
  u16* WhhT_l = (u16*)alloc((size_t)2 * HG * H_DIM * 2);
  u16* hWT_h  = (u16*)alloc((size_t)2 * A_DIM * H_DIM * 2);
  u16* hWT_l  = (u16*)alloc((size_t)2 * A_DIM * H_DIM * 2);
  int* indb   = (int*)alloc((size_t)NHEADS * NSTEPS * B_DIM * 4);
  float* t1 = gi2;            // MLP temps (gi2/gh2 free pre-loop)
  float* t2 = gh2;

  dim3 blk(256);

  // weight transpose+split (once per launch; weights constant)
  transpose_split<<<dim3(HG / 32, H_DIM / 32, 2), blk, 0, stream>>>(
      gWih, WihT_h, WihT_l, H_DIM, HG, (size_t)H_DIM * HG, (size_t)HG * H_DIM);
  transpose_split<<<dim3(HG / 32, H_DIM / 32, 2), blk, 0, stream>>>(
      gWhh, WhhT_h, WhhT_l, H_DIM, HG, (size_t)H_DIM * HG, (size_t)HG * H_DIM);
  transpose_split<<<dim3((A_DIM + 31) / 32, H_DIM / 32, 2), blk, 0, stream>>>(
      hW, hWT_h, hWT_l, H_DIM, A_DIM, (size_t)H_DIM * A_DIM, (size_t)A_DIM * H_DIM);

  // MLP: cls = (relu(relu(x@W1+b1)@W2+b2))@W3 + b3  (fp32 exact)
  auto gemm64 = [&](const float* Am, const float* Bm, const float* bias, float* Cm,
                    int M, int N, int K, int act) {
    dim3 grid((N + 63) / 64, M / 64);
    gemm_bias_act<<<grid, blk, 0, stream>>>(Am, Bm, bias, Cm, M, N, K, act);
  };
  gemm64(x, W1, b1, t1, B_DIM, H_DIM, DIN, 1);
  gemm64(t1, W2, b2, t2, B_DIM, H_DIM, H_DIM, 1);
  gemm64(t2, W3, b3, cls, B_DIM, H_DIM, H_DIM, 0);

  init_state_kernel<<<(2 * BH + 255) / 256, blk, 0, stream>>>(cls, h2, h_hi, h_lo, cur_hi, cur_lo);

  // host-side key schedule: key(42) -> fold_in(head) -> fold_in(step)
  uint32_t bk0 = 0u, bk1 = 42u;
  uint32_t hk[2][2];
  threefry2x32(bk0, bk1, 0u, 0u, hk[0][0], hk[0][1]);
  threefry2x32(bk0, bk1, 0u, 1u, hk[1][0], hk[1][1]);

  for (int j = 0; j < NSTEPS; ++j) {
    // gates GEMM, z=4: {h0:gi, h0:gh, h1:gi, h1:gh}, N=2304, bf16x3
    GemmS gb;
    for (int head = 0; head < NHEADS; ++head) {
      gb.Ah[head * 2 + 0] = cur_hi + (size_t)head * BH;
      gb.Al[head * 2 + 0] = cur_lo + (size_t)head * BH;
      gb.Bh[head * 2 + 0] = WihT_h + (size_t)head * HG * H_DIM;
      gb.Bl[head * 2 + 0] = WihT_l + (size_t)head * HG * H_DIM;
      gb.bias[head * 2 + 0] = gbih + (size_t)head * HG;
      gb.C[head * 2 + 0] = gi2 + (size_t)head * B_DIM * HG;
      gb.Ah[head * 2 + 1] = h_hi + (size_t)head * BH;
      gb.Al[head * 2 + 1] = h_lo + (size_t)head * BH;
      gb.Bh[head * 2 + 1] = WhhT_h + (size_t)head * HG * H_DIM;
      gb.Bl[head * 2 + 1] = WhhT_l + (size_t)head * HG * H_DIM;
      gb.bias[head * 2 + 1] = gbhh + (size_t)head * HG;
      gb.C[head * 2 + 1] = gh2 + (size_t)head * B_DIM * HG;
    }
    gemm_mfma<<<dim3((HG / 128) * (B_DIM / 128), 4), blk, 0, stream>>>(
        gb, H_DIM, HG, HG, (long long)HG, HG / 128, B_DIM / 128);

    gru_combine_kernel<<<(2 * BH + 255) / 256, blk, 0, stream>>>(gi2, gh2, h2, h_hi, h_lo);

    // logits GEMM, z=2: N=5001 (40 n-blocks), C into probs rows
    GemmS lb;
    for (int head = 0; head < NHEADS; ++head) {
      lb.Ah[head] = h_hi + (size_t)head * BH;
      lb.Al[head] = h_lo + (size_t)head * BH;
      lb.Bh[head] = hWT_h + (size_t)head * A_DIM * H_DIM;
      lb.Bl[head] = hWT_l + (size_t)head * A_DIM * H_DIM;
      lb.bias[head] = hb + (size_t)head * A_DIM;
      lb.C[head] = probs + (size_t)(head * NSTEPS + j) * A_DIM;
      lb.Ah[head + 2] = lb.Ah[head]; lb.Al[head + 2] = lb.Al[head];
      lb.Bh[head + 2] = lb.Bh[head]; lb.Bl[head + 2] = lb.Bl[head];
      lb.bias[head + 2] = lb.bias[head]; lb.C[head + 2] = lb.C[head];
    }
    gemm_mfma<<<dim3(40 * (B_DIM / 128), 2), blk, 0, stream>>>(
        lb, H_DIM, A_DIM, A_DIM, (long long)NHEADS * NSTEPS * A_DIM, 40, B_DIM / 128);

    uint32_t s00, s01, s10, s11;
    threefry2x32(hk[0][0], hk[0][1], 0u, (uint32_t)j, s00, s01);
    threefry2x32(hk[1][0], hk[1][1], 0u, (uint32_t)j, s10, s11);
    uint4 keys; keys.x = s00; keys.y = s01; keys.z = s10; keys.w = s11;
    sample_kernel<<<dim3(B_DIM, NHEADS), dim3(STH), 0, stream>>>(probs, xmask, indb, j, keys);

    if (j < NSTEPS - 1)
      curin_kernel<<<(2 * BH + 255) / 256, blk, 0, stream>>>(cls, ae_w, indb, j, cur_hi, cur_lo);
  }

  head_final_kernel<<<(NHEADS * B_DIM + 255) / 256, blk, 0, stream>>>(
      indb, Wmu, bmu, Wcov, bcov, alpha, matcp);
  final_out_kernel<<<(B_DIM * C_DIM + 255) / 256, blk, 0, stream>>>(matcp, out);
}

// Round 4
// 1003.190 us; speedup vs baseline: 3.0146x; 2.2037x over previous
//
#include <hip/hip_runtime.h>
#include <hip/hip_bf16.h>
#include <stdint.h>
#include <stddef.h>

#define B_DIM   1024
#define DIN     512
#define H_DIM   768
#define A_DIM   5001
#define NHEADS  2
#define NSTEPS  4
#define C_DIM   2
#define NEG_VAL -1e30f
#define BH      (B_DIM * H_DIM)

typedef unsigned short u16;
typedef __attribute__((ext_vector_type(8))) short v8s;
typedef __attribute__((ext_vector_type(4))) float v4f;

typedef const __attribute__((address_space(1))) uint32_t* gas_ptr;
typedef __attribute__((address_space(3))) uint32_t* las_ptr;

__device__ __forceinline__ void load_lds16(const void* g, void* l) {
  // async global->LDS DMA, 16B per lane; LDS dest is wave-uniform base + lane*16
  __builtin_amdgcn_global_load_lds((gas_ptr)g, (las_ptr)l, 16, 0, 0);
}

// ------------------------- Threefry-2x32 (JAX-compatible) -------------------------
__host__ __device__ inline uint32_t rotl32(uint32_t x, int d) {
  return (x << d) | (x >> (32 - d));
}

__host__ __device__ inline void threefry2x32(uint32_t k0, uint32_t k1,
                                             uint32_t x0, uint32_t x1,
                                             uint32_t& o0, uint32_t& o1) {
  uint32_t ks2 = k0 ^ k1 ^ 0x1BD11BDAu;
  x0 += k0; x1 += k1;
#define TFR(d) { x0 += x1; x1 = rotl32(x1, (d)); x1 ^= x0; }
  TFR(13) TFR(15) TFR(26) TFR(6)  x0 += k1;  x1 += ks2 + 1u;
  TFR(17) TFR(29) TFR(16) TFR(24) x0 += ks2; x1 += k0 + 2u;
  TFR(13) TFR(15) TFR(26) TFR(6)  x0 += k0;  x1 += k1 + 3u;
  TFR(17) TFR(29) TFR(16) TFR(24) x0 += k1;  x1 += ks2 + 4u;
  TFR(13) TFR(15) TFR(26) TFR(6)  x0 += ks2; x1 += k0 + 5u;
#undef TFR
  o0 = x0; o1 = x1;
}

__device__ inline float gumbel_noise(uint32_t k0, uint32_t k1, uint32_t idx) {
  uint32_t o0, o1;
  threefry2x32(k0, k1, 0u, idx, o0, o1);
  uint32_t bits = o0 ^ o1;
  float f = __uint_as_float(0x3f800000u | (bits >> 9)) - 1.0f;   // [0,1)
  float u = fmaxf(1e-9f, f * (1.0f - 1e-9f) + 1e-9f);            // jax.random.uniform
  return -logf(-logf(u));                                        // Gumbel(0,1)
}

// XLA logistic lowering: 0.5 + 0.5 * tanh(0.5 * x)
__device__ inline float sigmoidf_(float x) { return 0.5f * tanhf(0.5f * x) + 0.5f; }

__device__ inline void split_bf16(float x, u16& hi, u16& lo) {
  __hip_bfloat16 h = __float2bfloat16(x);
  float hf = __bfloat162float(h);
  __hip_bfloat16 l = __float2bfloat16(x - hf);
  hi = *(const u16*)&h;
  lo = *(const u16*)&l;
}

// ------------------------- small fp32 GEMM (MLP): 64x64 tile, 4x4/thread -------------------------
__global__ __launch_bounds__(256) void gemm_bias_act(
    const float* __restrict__ A, const float* __restrict__ B,
    const float* __restrict__ bias, float* __restrict__ C,
    int M, int N, int K, int act) {
  __shared__ float As[16][65];
  __shared__ float Bs[16][64];
  int tid = threadIdx.x;
  int bm = blockIdx.y * 64, bn = blockIdx.x * 64;
  int tx = tid & 15, ty = tid >> 4;
  float acc[4][4] = {};
  for (int k0 = 0; k0 < K; k0 += 16) {
#pragma unroll
    for (int r = 0; r < 4; ++r) {
      int m = (tid >> 4) + r * 16;
      int k = tid & 15;
      As[k][m] = A[(size_t)(bm + m) * K + k0 + k];
    }
#pragma unroll
    for (int r = 0; r < 4; ++r) {
      int n = tid & 63;
      int k = (tid >> 6) + r * 4;
      int gn = bn + n;
      Bs[k][n] = (gn < N) ? B[(size_t)(k0 + k) * N + gn] : 0.0f;
    }
    __syncthreads();
#pragma unroll
    for (int kk = 0; kk < 16; ++kk) {
      float a[4], bb[4];
#pragma unroll
      for (int i = 0; i < 4; ++i) a[i] = As[kk][ty * 4 + i];
#pragma unroll
      for (int jj = 0; jj < 4; ++jj) bb[jj] = Bs[kk][tx * 4 + jj];
#pragma unroll
      for (int i = 0; i < 4; ++i)
#pragma unroll
        for (int jj = 0; jj < 4; ++jj) acc[i][jj] = fmaf(a[i], bb[jj], acc[i][jj]);
    }
    __syncthreads();
  }
#pragma unroll
  for (int i = 0; i < 4; ++i) {
    int m = bm + ty * 4 + i;
#pragma unroll
    for (int jj = 0; jj < 4; ++jj) {
      int n = bn + tx * 4 + jj;
      if (n < N) {
        float v = acc[i][jj] + bias[n];
        if (act == 1) v = fmaxf(v, 0.0f);
        C[(size_t)m * N + n] = v;
      }
    }
  }
}

// ------------------------- weight transpose + bf16 split: W[K][N] -> hi/lo[N][K] -------------------------
__global__ __launch_bounds__(256) void transpose_split(
    const float* __restrict__ W, u16* __restrict__ hi, u16* __restrict__ lo,
    int K, int N, size_t inStride, size_t outStride) {
  const int e = blockIdx.z;
  const float* Win = W + (size_t)e * inStride;
  u16* ho = hi + (size_t)e * outStride;
  u16* loo = lo + (size_t)e * outStride;
  __shared__ float tile[32][33];
  const int k0 = blockIdx.y * 32, n0 = blockIdx.x * 32;
  const int tx = threadIdx.x & 31, ty = threadIdx.x >> 5;
#pragma unroll
  for (int r = ty; r < 32; r += 8) {
    int n = n0 + tx;
    tile[r][tx] = (n < N) ? Win[(size_t)(k0 + r) * N + n] : 0.0f;
  }
  __syncthreads();
#pragma unroll
  for (int r = ty; r < 32; r += 8) {
    int n = n0 + r, k = k0 + tx;
    if (n < N) {
      u16 h, l;
      split_bf16(tile[tx][r], h, l);
      ho[(size_t)n * K + k] = h;
      loo[(size_t)n * K + k] = l;
    }
  }
}

// ------------------------- bf16x3 MFMA GEMM: 128x128 tile, 4 waves, BK=32 -------------------------
// Staging via global_load_lds (16B/lane DMA). LDS layout linear [row][32 u16];
// XOR swizzle slot^((row>>1)&3) applied on the GLOBAL source and on the ds_read side.
struct GemmS {
  const u16* Ah[4]; const u16* Al[4];
  const u16* Bh[4]; const u16* Bl[4];
  const float* bias[4]; float* C[4];
};

__global__ __launch_bounds__(256, 2) void gemm_mfma(
    GemmS gs, int K, int N, int Nclamp, long long ldc, int nbx, int nby) {
  const int e = blockIdx.y;
  // XCD-chunked, m-fastest block ordering (nbx*nby divisible by 8)
  const int nwg = nbx * nby;
  const int chunk = nwg >> 3;
  const int orig = blockIdx.x;
  const int lid = (orig & 7) * chunk + (orig >> 3);
  const int by = lid % nby;
  const int bx = lid / nby;
  const int bm = by * 128, bn = bx * 128;

  __shared__ __align__(16) u16 lds[4][128 * 32];  // Ahi, Alo, Bhi, Blo (8KB each)

  const int tid = threadIdx.x;
  const int wv = tid >> 6, ln = tid & 63;
  const int wr = wv >> 1, wc = wv & 1;     // wave 2x2 grid for compute
  const int lk = ln >> 4;                  // k-group 0..3
  const int lm = ln & 15;                  // frag row/col
  const int fswz = (lm >> 1) & 3;          // read-side XOR swizzle

  // staging: wave wv DMAs tensor wv; per issue i rows i*16+(ln>>2)
  const int lrow = ln >> 2;                          // 0..15
  const int slot = (ln & 3) ^ ((lrow >> 1) & 3);     // issue-invariant source swizzle
  const u16* tsrc = (wv == 0) ? gs.Ah[e] : (wv == 1) ? gs.Al[e]
                  : (wv == 2) ? gs.Bh[e] : gs.Bl[e];
  const int isB = (wv >= 2);
  const int rowbase = isB ? bn : bm;

  const float* bias = gs.bias[e];
  float* C = gs.C[e];

  v4f acc[4][4];
#pragma unroll
  for (int i = 0; i < 4; ++i)
#pragma unroll
    for (int j = 0; j < 4; ++j) acc[i][j] = (v4f){0.f, 0.f, 0.f, 0.f};

  for (int k0 = 0; k0 < K; k0 += 32) {
#pragma unroll
    for (int i = 0; i < 8; ++i) {
      int gr = rowbase + i * 16 + lrow;
      if (isB && gr >= Nclamp) gr = Nclamp - 1;      // OOB N rows: duplicate last (C-write guarded)
      const u16* gp = tsrc + (size_t)gr * K + k0 + slot * 8;
      load_lds16(gp, (void*)&lds[wv][i * 512]);
    }
    __syncthreads();   // compiler drains vmcnt(0) before barrier (m97 pattern)

    v8s ah[4], al[4], bh[4], bl[4];
#pragma unroll
    for (int mi = 0; mi < 4; ++mi) {
      const int r = wr * 64 + mi * 16 + lm;
      const int off = r * 32 + ((lk ^ fswz) * 8);
      ah[mi] = *(const v8s*)&lds[0][off];
      al[mi] = *(const v8s*)&lds[1][off];
    }
#pragma unroll
    for (int ni = 0; ni < 4; ++ni) {
      const int r = wc * 64 + ni * 16 + lm;
      const int off = r * 32 + ((lk ^ fswz) * 8);
      bh[ni] = *(const v8s*)&lds[2][off];
      bl[ni] = *(const v8s*)&lds[3][off];
    }
    // 3-term split product, 16-MFMA spacing between same-acc uses
#pragma unroll
    for (int mi = 0; mi < 4; ++mi)
#pragma unroll
      for (int ni = 0; ni < 4; ++ni)
        acc[mi][ni] = __builtin_amdgcn_mfma_f32_16x16x32_bf16(ah[mi], bh[ni], acc[mi][ni], 0, 0, 0);
#pragma unroll
    for (int mi = 0; mi < 4; ++mi)
#pragma unroll
      for (int ni = 0; ni < 4; ++ni)
        acc[mi][ni] = __builtin_amdgcn_mfma_f32_16x16x32_bf16(ah[mi], bl[ni], acc[mi][ni], 0, 0, 0);
#pragma unroll
    for (int mi = 0; mi < 4; ++mi)
#pragma unroll
      for (int ni = 0; ni < 4; ++ni)
        acc[mi][ni] = __builtin_amdgcn_mfma_f32_16x16x32_bf16(al[mi], bh[ni], acc[mi][ni], 0, 0, 0);

    __syncthreads();   // protect LDS before next tile's DMA
  }

  // epilogue: C/D layout col=lane&15, row=(lane>>4)*4+reg (m89-verified)
#pragma unroll
  for (int mi = 0; mi < 4; ++mi) {
    const int m = bm + wr * 64 + mi * 16 + lk * 4;
#pragma unroll
    for (int ni = 0; ni < 4; ++ni) {
      const int n = bn + wc * 64 + ni * 16 + lm;
      if (n < N) {
        const float bv = bias[n];
        float* cp = C + (size_t)m * ldc + n;
#pragma unroll
        for (int r = 0; r < 4; ++r)
          cp[(size_t)r * ldc] = acc[mi][ni][r] + bv;
      }
    }
  }
}

// ------------------------- init per-head state: h=0 (+split), cur=cls (+split) -------------------------
__global__ __launch_bounds__(256) void init_state_kernel(
    const float* __restrict__ cls, float* __restrict__ h2,
    u16* __restrict__ h_hi, u16* __restrict__ h_lo,
    u16* __restrict__ cur_hi, u16* __restrict__ cur_lo) {
  int idx = blockIdx.x * blockDim.x + threadIdx.x;
  if (idx >= 2 * BH) return;
  int rem = idx % BH;
  h2[idx] = 0.0f;
  h_hi[idx] = 0; h_lo[idx] = 0;
  u16 h, l;
  split_bf16(cls[rem], h, l);
  cur_hi[idx] = h; cur_lo[idx] = l;
}

// ------------------------- GRU gate combine (both heads) + h split -------------------------
__global__ __launch_bounds__(256) void gru_combine_kernel(
    const float* __restrict__ gi2, const float* __restrict__ gh2, float* __restrict__ h2,
    u16* __restrict__ h_hi, u16* __restrict__ h_lo) {
  int idx = blockIdx.x * blockDim.x + threadIdx.x;
  if (idx >= 2 * BH) return;
  int e = idx / BH, rem = idx % BH;
  int b = rem / H_DIM, c = rem - b * H_DIM;
  const float* gib = gi2 + ((size_t)e * B_DIM + b) * 3 * H_DIM;
  const float* ghb = gh2 + ((size_t)e * B_DIM + b) * 3 * H_DIM;
  float ir = gib[c], iz = gib[H_DIM + c], inn = gib[2 * H_DIM + c];
  float hr = ghb[c], hz = ghb[H_DIM + c], hn = ghb[2 * H_DIM + c];
  float r = sigmoidf_(ir + hr);
  float z = sigmoidf_(iz + hz);
  float n = tanhf(inn + r * hn);
  float hv = (1.0f - z) * n + z * h2[idx];
  h2[idx] = hv;
  u16 h, l;
  split_bf16(hv, h, l);
  h_hi[idx] = h; h_lo[idx] = l;
}

// ------------------------- cur_in = cls + ae_w[ind] (both heads), split output -------------------------
__global__ __launch_bounds__(256) void curin_kernel(
    const float* __restrict__ cls, const float* __restrict__ ae_w,
    const int* __restrict__ indb, int j,
    u16* __restrict__ cur_hi, u16* __restrict__ cur_lo) {
  int idx = blockIdx.x * blockDim.x + threadIdx.x;
  if (idx >= 2 * BH) return;
  int e = idx / BH, rem = idx % BH;
  int b = rem / H_DIM, c = rem - b * H_DIM;
  int ind = indb[(e * NSTEPS + j) * B_DIM + b];
  float v = cls[rem] + ae_w[(size_t)ind * H_DIM + c];
  u16 h, l;
  split_bf16(v, h, l);
  cur_hi[idx] = h; cur_lo[idx] = l;
}

// ------------------------- sampling (both heads), in-place on probs rows -------------------------
#define STH 256
#define PER_TH 20  // ceil(5001/256)

__global__ __launch_bounds__(STH) void sample_kernel(
    float* __restrict__ probs, const int* __restrict__ x_mask,
    int* __restrict__ indb, int j, uint4 keys) {
  int b = blockIdx.x;
  int e = blockIdx.y;
  int t = threadIdx.x;
  uint32_t k0 = (e == 0) ? keys.x : keys.z;
  uint32_t k1 = (e == 0) ? keys.y : keys.w;
  __shared__ float rv[STH];
  __shared__ int ri[STH];
  __shared__ int s_ind;

  float* prow = probs + (((size_t)b * NHEADS + e) * NSTEPS + j) * A_DIM;
  const int* mrow = x_mask + (size_t)b * A_DIM;

  int prev[3];
  bool dead = false;
  for (int tt = 0; tt < j; ++tt) {
    prev[tt] = indb[(e * NSTEPS + tt) * B_DIM + b];
    if (prev[tt] == 0) dead = true;
  }

  bool rowany = true;
  if (j == 0) {
    int any = 0;
    for (int a = t; a < A_DIM; a += STH) any |= mrow[a];
    ri[t] = any; __syncthreads();
    for (int s = STH / 2; s > 0; s >>= 1) {
      if (t < s) ri[t] |= ri[t + s];
      __syncthreads();
    }
    rowany = (ri[0] != 0);
    __syncthreads();
  }

  float v[PER_TH];
  float lmax = -3.0e38f;
#pragma unroll
  for (int s = 0; s < PER_TH; ++s) {
    int a = t + s * STH;
    float val = -3.0e38f;
    if (a < A_DIM) {
      int m;
      if (j == 0) {
        m = (a == 0) ? (rowany ? mrow[0] : 1) : mrow[a];
      } else if (a == 0) {
        m = 1;
      } else if (dead) {
        m = 0;
      } else {
        m = mrow[a];
        if (m) {
          for (int tt = 0; tt < j; ++tt)
            if (prev[tt] == a) { m = 0; break; }
        }
      }
      if (m > 0)
        val = prow[a] + gumbel_noise(k0, k1, (uint32_t)(b * A_DIM + a));
    }
    v[s] = val;
    lmax = fmaxf(lmax, val);
  }

  rv[t] = lmax; __syncthreads();
  for (int s = STH / 2; s > 0; s >>= 1) {
    if (t < s) rv[t] = fmaxf(rv[t], rv[t + s]);
    __syncthreads();
  }
  float m = rv[0]; __syncthreads();

  float lsum = 0.0f;
#pragma unroll
  for (int s = 0; s < PER_TH; ++s) {
    int a = t + s * STH;
    float ev = (a < A_DIM && v[s] > -1.0e37f) ? expf(v[s] - m) : 0.0f;
    v[s] = ev; lsum += ev;
  }
  rv[t] = lsum; __syncthreads();
  for (int s = STH / 2; s > 0; s >>= 1) {
    if (t < s) rv[t] += rv[t + s];
    __syncthreads();
  }
  float ssum = rv[0]; __syncthreads();

  float besty = -1.0f; int besti = A_DIM;
#pragma unroll
  for (int s = 0; s < PER_TH; ++s) {
    int a = t + s * STH;
    if (a < A_DIM) {
      float y = v[s] / ssum;
      if (y > besty) { besty = y; besti = a; }
    }
  }
  rv[t] = besty; ri[t] = besti; __syncthreads();
  for (int s = STH / 2; s > 0; s >>= 1) {
    if (t < s) {
      float y2 = rv[t + s]; int i2 = ri[t + s];
      if (y2 > rv[t] || (y2 == rv[t] && i2 < ri[t])) { rv[t] = y2; ri[t] = i2; }
    }
    __syncthreads();
  }
  if (t == 0) { s_ind = ri[0]; indb[(e * NSTEPS + j) * B_DIM + b] = ri[0]; }
  __syncthreads();
  int ind = s_ind;

  for (int a = t; a < A_DIM; a += STH) prow[a] = (a == ind) ? 1.0f : 0.0f;
}

// ------------------------- per-head consequent estimator (both heads) -------------------------
__global__ __launch_bounds__(256) void head_final_kernel(
    const int* __restrict__ indb, const float* __restrict__ Wmu,
    const float* __restrict__ bmu, const float* __restrict__ Wcov,
    const float* __restrict__ bcov, const float* __restrict__ alpha,
    float* __restrict__ matcp) {
  int idx = blockIdx.x * blockDim.x + threadIdx.x;
  if (idx >= NHEADS * B_DIM) return;
  int e = idx / B_DIM, b = idx - e * B_DIM;
  float a0 = 0.0f, a1 = 0.0f, ac = 0.0f;
  for (int j = 0; j < NSTEPS; ++j) {
    int ind = indb[(e * NSTEPS + j) * B_DIM + b];
    a0 += 0.25f * Wmu[(size_t)ind * C_DIM + 0];
    a1 += 0.25f * Wmu[(size_t)ind * C_DIM + 1];
    ac += 0.25f * Wcov[ind];
  }
  float mu0 = sigmoidf_(a0 + bmu[0]);
  float mu1 = sigmoidf_(a1 + bmu[1]);
  float cov = sigmoidf_(ac + bcov[0]);
  float n = cov * 56000.0f;
  float sf = alpha[0] / n;
  float denom = 1.0f + 2.0f * sf;
  matcp[((size_t)b * NHEADS + e) * C_DIM + 0] = (mu0 + sf) / denom;
  matcp[((size_t)b * NHEADS + e) * C_DIM + 1] = (mu1 + sf) / denom;
}

__global__ __launch_bounds__(256) void final_out_kernel(
    const float* __restrict__ matcp, float* __restrict__ out) {
  int idx = blockIdx.x * blockDim.x + threadIdx.x;
  if (idx >= B_DIM * C_DIM) return;
  int b = idx / C_DIM, c = idx - b * C_DIM;
  float s = matcp[((size_t)b * NHEADS + 0) * C_DIM + c] +
            matcp[((size_t)b * NHEADS + 1) * C_DIM + c];
  out[idx] = logf(s * 0.5f);
}

// ------------------------- orchestration -------------------------
extern "C" void kernel_launch(void* const* d_in, const int* in_sizes, int n_in,
                              void* d_out, int out_size, void* d_ws, size_t ws_size,
                              hipStream_t stream) {
  const float* x     = (const float*)d_in[0];
  const int*   xmask = (const int*)d_in[1];
  const float* W1 = (const float*)d_in[2];  const float* b1 = (const float*)d_in[3];
  const float* W2 = (const float*)d_in[4];  const float* b2 = (const float*)d_in[5];
  const float* W3 = (const float*)d_in[6];  const float* b3 = (const float*)d_in[7];
  const float* gWih = (const float*)d_in[8];  const float* gWhh = (const float*)d_in[9];
  const float* gbih = (const float*)d_in[10]; const float* gbhh = (const float*)d_in[11];
  const float* hW = (const float*)d_in[12];   const float* hb = (const float*)d_in[13];
  const float* ae_w = (const float*)d_in[14];
  const float* Wmu  = (const float*)d_in[15]; const float* bmu  = (const float*)d_in[16];
  const float* Wcov = (const float*)d_in[17]; const float* bcov = (const float*)d_in[18];
  const float* alpha = (const float*)d_in[19];

  float* out = (float*)d_out;
  float* probs = out + (size_t)B_DIM * C_DIM;                       // [B, 2, 4, A]
  float* matcp = probs + (size_t)B_DIM * NHEADS * NSTEPS * A_DIM;   // [B, 2, C]

  const int HG = 3 * H_DIM;   // 2304
  uint8_t* wsp = (uint8_t*)d_ws;
  auto alloc = [&](size_t bytes) {
    uint8_t* p = wsp;
    wsp += (bytes + 255) & ~(size_t)255;
    return p;
  };
  float* cls  = (float*)alloc((size_t)BH * 4);
  float* h2   = (float*)alloc((size_t)2 * BH * 4);
  float* gi2  = (float*)alloc((size_t)2 * B_DIM * HG * 4);
  float* gh2  = (float*)alloc((size_t)2 * B_DIM * HG * 4);
  u16* h_hi   = (u16*)alloc((size_t)2 * BH * 2);
  u16* h_lo   = (u16*)alloc((size_t)2 * BH * 2);
  u16* cur_hi = (u16*)alloc((size_t)2 * BH * 2);
  u16* cur_lo = (u16*)alloc((size_t)2 * BH * 2);
  u16* WihT_h = (u16*)alloc((size_t)2 * HG * H_DIM * 2);
  u16* WihT_l = (u16*)alloc((size_t)2 * HG * H_DIM * 2);
  u16* WhhT_h = (u16*)alloc((size_t)2 * HG * H_DIM * 2);
  u16* WhhT_l = (u16*)alloc((size_t)2 * HG * H_DIM * 2);
  u16* hWT_h  = (u16*)alloc((size_t)2 * A_DIM * H_DIM * 2);
  u16* hWT_l  = (u16*)alloc((size_t)2 * A_DIM * H_DIM * 2);
  int* indb   = (int*)alloc((size_t)NHEADS * NSTEPS * B_DIM * 4);
  float* t1 = gi2;            // MLP temps (gi2/gh2 free pre-loop)
  float* t2 = gh2;

  dim3 blk(256);

  // weight transpose+split (once per launch; weights constant)
  transpose_split<<<dim3(HG / 32, H_DIM / 32, 2), blk, 0, stream>>>(
      gWih, WihT_h, WihT_l, H_DIM, HG, (size_t)H_DIM * HG, (size_t)HG * H_DIM);
  transpose_split<<<dim3(HG / 32, H_DIM / 32, 2), blk, 0, stream>>>(
      gWhh, WhhT_h, WhhT_l, H_DIM, HG, (size_t)H_DIM * HG, (size_t)HG * H_DIM);
  transpose_split<<<dim3((A_DIM + 31) / 32, H_DIM / 32, 2), blk, 0, stream>>>(
      hW, hWT_h, hWT_l, H_DIM, A_DIM, (size_t)H_DIM * A_DIM, (size_t)A_DIM * H_DIM);

  // MLP: cls = (relu(relu(x@W1+b1)@W2+b2))@W3 + b3  (fp32 exact)
  auto gemm64 = [&](const float* Am, const float* Bm, const float* bias, float* Cm,
                    int M, int N, int K, int act) {
    dim3 grid((N + 63) / 64, M / 64);
    gemm_bias_act<<<grid, blk, 0, stream>>>(Am, Bm, bias, Cm, M, N, K, act);
  };
  gemm64(x, W1, b1, t1, B_DIM, H_DIM, DIN, 1);
  gemm64(t1, W2, b2, t2, B_DIM, H_DIM, H_DIM, 1);
  gemm64(t2, W3, b3, cls, B_DIM, H_DIM, H_DIM, 0);

  init_state_kernel<<<(2 * BH + 255) / 256, blk, 0, stream>>>(cls, h2, h_hi, h_lo, cur_hi, cur_lo);

  // host-side key schedule: key(42) -> fold_in(head) -> fold_in(step)
  uint32_t bk0 = 0u, bk1 = 42u;
  uint32_t hk[2][2];
  threefry2x32(bk0, bk1, 0u, 0u, hk[0][0], hk[0][1]);
  threefry2x32(bk0, bk1, 0u, 1u, hk[1][0], hk[1][1]);

  for (int j = 0; j < NSTEPS; ++j) {
    // gates GEMM, z=4: {h0:gi, h0:gh, h1:gi, h1:gh}, N=2304, bf16x3
    GemmS gb;
    for (int head = 0; head < NHEADS; ++head) {
      gb.Ah[head * 2 + 0] = cur_hi + (size_t)head * BH;
      gb.Al[head * 2 + 0] = cur_lo + (size_t)head * BH;
      gb.Bh[head * 2 + 0] = WihT_h + (size_t)head * HG * H_DIM;
      gb.Bl[head * 2 + 0] = WihT_l + (size_t)head * HG * H_DIM;
      gb.bias[head * 2 + 0] = gbih + (size_t)head * HG;
      gb.C[head * 2 + 0] = gi2 + (size_t)head * B_DIM * HG;
      gb.Ah[head * 2 + 1] = h_hi + (size_t)head * BH;
      gb.Al[head * 2 + 1] = h_lo + (size_t)head * BH;
      gb.Bh[head * 2 + 1] = WhhT_h + (size_t)head * HG * H_DIM;
      gb.Bl[head * 2 + 1] = WhhT_l + (size_t)head * HG * H_DIM;
      gb.bias[head * 2 + 1] = gbhh + (size_t)head * HG;
      gb.C[head * 2 + 1] = gh2 + (size_t)head * B_DIM * HG;
    }
    gemm_mfma<<<dim3((HG / 128) * (B_DIM / 128), 4), blk, 0, stream>>>(
        gb, H_DIM, HG, HG, (long long)HG, HG / 128, B_DIM / 128);

    gru_combine_kernel<<<(2 * BH + 255) / 256, blk, 0, stream>>>(gi2, gh2, h2, h_hi, h_lo);

    // logits GEMM, z=2: N=5001 (40 n-blocks), C into probs rows
    GemmS lb;
    for (int head = 0; head < NHEADS; ++head) {
      lb.Ah[head] = h_hi + (size_t)head * BH;
      lb.Al[head] = h_lo + (size_t)head * BH;
      lb.Bh[head] = hWT_h + (size_t)head * A_DIM * H_DIM;
      lb.Bl[head] = hWT_l + (size_t)head * A_DIM * H_DIM;
      lb.bias[head] = hb + (size_t)head * A_DIM;
      lb.C[head] = probs + (size_t)(head * NSTEPS + j) * A_DIM;
      lb.Ah[head + 2] = lb.Ah[head]; lb.Al[head + 2] = lb.Al[head];
      lb.Bh[head + 2] = lb.Bh[head]; lb.Bl[head + 2] = lb.Bl[head];
      lb.bias[head + 2] = lb.bias[head]; lb.C[head + 2] = lb.C[head];
    }
    gemm_mfma<<<dim3(40 * (B_DIM / 128), 2), blk, 0, stream>>>(
        lb, H_DIM, A_DIM, A_DIM, (long long)NHEADS * NSTEPS * A_DIM, 40, B_DIM / 128);

    uint32_t s00, s01, s10, s11;
    threefry2x32(hk[0][0], hk[0][1], 0u, (uint32_t)j, s00, s01);
    threefry2x32(hk[1][0], hk[1][1], 0u, (uint32_t)j, s10, s11);
    uint4 keys; keys.x = s00; keys.y = s01; keys.z = s10; keys.w = s11;
    sample_kernel<<<dim3(B_DIM, NHEADS), dim3(STH), 0, stream>>>(probs, xmask, indb, j, keys);

    if (j < NSTEPS - 1)
      curin_kernel<<<(2 * BH + 255) / 256, blk, 0, stream>>>(cls, ae_w, indb, j, cur_hi, cur_lo);
  }

  head_final_kernel<<<(NHEADS * B_DIM + 255) / 256, blk, 0, stream>>>(
      indb, Wmu, bmu, Wcov, bcov, alpha, matcp);
  final_out_kernel<<<(B_DIM * C_DIM + 255) / 256, blk, 0, stream>>>(matcp, out);
}

// Round 5
// 832.685 us; speedup vs baseline: 3.6319x; 1.2048x over previous
//
#include <hip/hip_runtime.h>
#include <hip/hip_bf16.h>
#include <stdint.h>
#include <stddef.h>

#define B_DIM   1024
#define DIN     512
#define H_DIM   768
#define A_DIM   5001
#define NHEADS  2
#define NSTEPS  4
#define C_DIM   2
#define NEG_VAL -1e30f
#define BH      (B_DIM * H_DIM)

typedef unsigned short u16;
typedef __attribute__((ext_vector_type(8))) short v8s;
typedef __attribute__((ext_vector_type(4))) float v4f;

typedef const __attribute__((address_space(1))) uint32_t* gas_ptr;
typedef __attribute__((address_space(3))) uint32_t* las_ptr;

__device__ __forceinline__ void load_lds16(const void* g, void* l) {
  // async global->LDS DMA, 16B per lane; LDS dest is wave-uniform base + lane*16
  __builtin_amdgcn_global_load_lds((gas_ptr)g, (las_ptr)l, 16, 0, 0);
}

// ------------------------- Threefry-2x32 (JAX-compatible) -------------------------
__host__ __device__ inline uint32_t rotl32(uint32_t x, int d) {
  return (x << d) | (x >> (32 - d));
}

__host__ __device__ inline void threefry2x32(uint32_t k0, uint32_t k1,
                                             uint32_t x0, uint32_t x1,
                                             uint32_t& o0, uint32_t& o1) {
  uint32_t ks2 = k0 ^ k1 ^ 0x1BD11BDAu;
  x0 += k0; x1 += k1;
#define TFR(d) { x0 += x1; x1 = rotl32(x1, (d)); x1 ^= x0; }
  TFR(13) TFR(15) TFR(26) TFR(6)  x0 += k1;  x1 += ks2 + 1u;
  TFR(17) TFR(29) TFR(16) TFR(24) x0 += ks2; x1 += k0 + 2u;
  TFR(13) TFR(15) TFR(26) TFR(6)  x0 += k0;  x1 += k1 + 3u;
  TFR(17) TFR(29) TFR(16) TFR(24) x0 += k1;  x1 += ks2 + 4u;
  TFR(13) TFR(15) TFR(26) TFR(6)  x0 += ks2; x1 += k0 + 5u;
#undef TFR
  o0 = x0; o1 = x1;
}

__device__ inline float gumbel_noise(uint32_t k0, uint32_t k1, uint32_t idx) {
  uint32_t o0, o1;
  threefry2x32(k0, k1, 0u, idx, o0, o1);
  uint32_t bits = o0 ^ o1;
  float f = __uint_as_float(0x3f800000u | (bits >> 9)) - 1.0f;   // [0,1)
  float u = fmaxf(1e-9f, f * (1.0f - 1e-9f) + 1e-9f);            // jax.random.uniform
  return -logf(-logf(u));                                        // Gumbel(0,1)
}

// XLA logistic lowering: 0.5 + 0.5 * tanh(0.5 * x)
__device__ inline float sigmoidf_(float x) { return 0.5f * tanhf(0.5f * x) + 0.5f; }

__device__ inline void split_bf16(float x, u16& hi, u16& lo) {
  __hip_bfloat16 h = __float2bfloat16(x);
  float hf = __bfloat162float(h);
  __hip_bfloat16 l = __float2bfloat16(x - hf);
  hi = *(const u16*)&h;
  lo = *(const u16*)&l;
}

// ------------------------- fp32 split-K GEMM (MLP): 64x64 tile, K-chunk per grid.z -------------------------
__global__ __launch_bounds__(256) void gemm_splitk(
    const float* __restrict__ A, const float* __restrict__ B,
    float* __restrict__ part, int M, int N, int K, int kchunk) {
  __shared__ float As[16][65];
  __shared__ float Bs[16][64];
  int tid = threadIdx.x;
  int bm = blockIdx.y * 64, bn = blockIdx.x * 64;
  const int s = blockIdx.z;
  const int kb = s * kchunk;
  const int ke = (kb + kchunk < K) ? (kb + kchunk) : K;
  int tx = tid & 15, ty = tid >> 4;
  float acc[4][4] = {};
  for (int k0 = kb; k0 < ke; k0 += 16) {
#pragma unroll
    for (int r = 0; r < 4; ++r) {
      int m = (tid >> 4) + r * 16;
      int k = tid & 15;
      As[k][m] = A[(size_t)(bm + m) * K + k0 + k];
    }
#pragma unroll
    for (int r = 0; r < 4; ++r) {
      int n = tid & 63;
      int k = (tid >> 6) + r * 4;
      int gn = bn + n;
      Bs[k][n] = (gn < N) ? B[(size_t)(k0 + k) * N + gn] : 0.0f;
    }
    __syncthreads();
#pragma unroll
    for (int kk = 0; kk < 16; ++kk) {
      float a[4], bb[4];
#pragma unroll
      for (int i = 0; i < 4; ++i) a[i] = As[kk][ty * 4 + i];
#pragma unroll
      for (int jj = 0; jj < 4; ++jj) bb[jj] = Bs[kk][tx * 4 + jj];
#pragma unroll
      for (int i = 0; i < 4; ++i)
#pragma unroll
        for (int jj = 0; jj < 4; ++jj) acc[i][jj] = fmaf(a[i], bb[jj], acc[i][jj]);
    }
    __syncthreads();
  }
  float* po = part + (size_t)s * M * N;
#pragma unroll
  for (int i = 0; i < 4; ++i) {
    int m = bm + ty * 4 + i;
#pragma unroll
    for (int jj = 0; jj < 4; ++jj) {
      int n = bn + tx * 4 + jj;
      if (n < N) po[(size_t)m * N + n] = acc[i][jj];
    }
  }
}

__global__ __launch_bounds__(256) void reduce_bias_act(
    const float* __restrict__ part, const float* __restrict__ bias,
    float* __restrict__ C, int M, int N, int S, int act) {
  int idx = blockIdx.x * blockDim.x + threadIdx.x;
  if (idx >= M * N) return;
  int n = idx % N;
  float v = 0.0f;
  for (int s = 0; s < S; ++s) v += part[(size_t)s * M * N + idx];
  v += bias[n];
  if (act == 1) v = fmaxf(v, 0.0f);
  C[idx] = v;
}

// ------------------------- weight transpose + bf16 split: W[K][N] -> hi/lo[N][K] -------------------------
__global__ __launch_bounds__(256) void transpose_split(
    const float* __restrict__ W, u16* __restrict__ hi, u16* __restrict__ lo,
    int K, int N, size_t inStride, size_t outStride) {
  const int e = blockIdx.z;
  const float* Win = W + (size_t)e * inStride;
  u16* ho = hi + (size_t)e * outStride;
  u16* loo = lo + (size_t)e * outStride;
  __shared__ float tile[32][33];
  const int k0 = blockIdx.y * 32, n0 = blockIdx.x * 32;
  const int tx = threadIdx.x & 31, ty = threadIdx.x >> 5;
#pragma unroll
  for (int r = ty; r < 32; r += 8) {
    int n = n0 + tx;
    tile[r][tx] = (n < N) ? Win[(size_t)(k0 + r) * N + n] : 0.0f;
  }
  __syncthreads();
#pragma unroll
  for (int r = ty; r < 32; r += 8) {
    int n = n0 + r, k = k0 + tx;
    if (n < N) {
      u16 h, l;
      split_bf16(tile[tx][r], h, l);
      ho[(size_t)n * K + k] = h;
      loo[(size_t)n * K + k] = l;
    }
  }
}

// ------------------------- bf16x3 MFMA GEMM: 128x128 tile, 4 waves, BK=32 -------------------------
// Staging via global_load_lds (16B/lane DMA). LDS layout linear [row][32 u16];
// XOR swizzle slot^((row>>1)&3) applied on the GLOBAL source and on the ds_read side.
struct GemmS {
  const u16* Ah[4]; const u16* Al[4];
  const u16* Bh[4]; const u16* Bl[4];
  const float* bias[4]; float* C[4];
};

__global__ __launch_bounds__(256, 2) void gemm_mfma(
    GemmS gs, int K, int N, int Nclamp, long long ldc, int nbx, int nby) {
  const int e = blockIdx.y;
  // XCD-chunked, m-fastest block ordering (nbx*nby divisible by 8)
  const int nwg = nbx * nby;
  const int chunk = nwg >> 3;
  const int orig = blockIdx.x;
  const int lid = (orig & 7) * chunk + (orig >> 3);
  const int by = lid % nby;
  const int bx = lid / nby;
  const int bm = by * 128, bn = bx * 128;

  __shared__ __align__(16) u16 lds[4][128 * 32];  // Ahi, Alo, Bhi, Blo (8KB each)

  const int tid = threadIdx.x;
  const int wv = tid >> 6, ln = tid & 63;
  const int wr = wv >> 1, wc = wv & 1;     // wave 2x2 grid for compute
  const int lk = ln >> 4;                  // k-group 0..3
  const int lm = ln & 15;                  // frag row/col
  const int fswz = (lm >> 1) & 3;          // read-side XOR swizzle

  // staging: wave wv DMAs tensor wv; per issue i rows i*16+(ln>>2)
  const int lrow = ln >> 2;                          // 0..15
  const int slot = (ln & 3) ^ ((lrow >> 1) & 3);     // issue-invariant source swizzle
  const u16* tsrc = (wv == 0) ? gs.Ah[e] : (wv == 1) ? gs.Al[e]
                  : (wv == 2) ? gs.Bh[e] : gs.Bl[e];
  const int isB = (wv >= 2);
  const int rowbase = isB ? bn : bm;

  const float* bias = gs.bias[e];
  float* C = gs.C[e];

  v4f acc[4][4];
#pragma unroll
  for (int i = 0; i < 4; ++i)
#pragma unroll
    for (int j = 0; j < 4; ++j) acc[i][j] = (v4f){0.f, 0.f, 0.f, 0.f};

  for (int k0 = 0; k0 < K; k0 += 32) {
#pragma unroll
    for (int i = 0; i < 8; ++i) {
      int gr = rowbase + i * 16 + lrow;
      if (isB && gr >= Nclamp) gr = Nclamp - 1;      // OOB N rows: duplicate last (C-write guarded)
      const u16* gp = tsrc + (size_t)gr * K + k0 + slot * 8;
      load_lds16(gp, (void*)&lds[wv][i * 512]);
    }
    __syncthreads();   // compiler drains vmcnt(0) before barrier (m97 pattern)

    v8s ah[4], al[4], bh[4], bl[4];
#pragma unroll
    for (int mi = 0; mi < 4; ++mi) {
      const int r = wr * 64 + mi * 16 + lm;
      const int off = r * 32 + ((lk ^ fswz) * 8);
      ah[mi] = *(const v8s*)&lds[0][off];
      al[mi] = *(const v8s*)&lds[1][off];
    }
#pragma unroll
    for (int ni = 0; ni < 4; ++ni) {
      const int r = wc * 64 + ni * 16 + lm;
      const int off = r * 32 + ((lk ^ fswz) * 8);
      bh[ni] = *(const v8s*)&lds[2][off];
      bl[ni] = *(const v8s*)&lds[3][off];
    }
    // 3-term split product
#pragma unroll
    for (int mi = 0; mi < 4; ++mi)
#pragma unroll
      for (int ni = 0; ni < 4; ++ni)
        acc[mi][ni] = __builtin_amdgcn_mfma_f32_16x16x32_bf16(ah[mi], bh[ni], acc[mi][ni], 0, 0, 0);
#pragma unroll
    for (int mi = 0; mi < 4; ++mi)
#pragma unroll
      for (int ni = 0; ni < 4; ++ni)
        acc[mi][ni] = __builtin_amdgcn_mfma_f32_16x16x32_bf16(ah[mi], bl[ni], acc[mi][ni], 0, 0, 0);
#pragma unroll
    for (int mi = 0; mi < 4; ++mi)
#pragma unroll
      for (int ni = 0; ni < 4; ++ni)
        acc[mi][ni] = __builtin_amdgcn_mfma_f32_16x16x32_bf16(al[mi], bh[ni], acc[mi][ni], 0, 0, 0);

    __syncthreads();   // protect LDS before next tile's DMA
  }

  // epilogue: C/D layout col=lane&15, row=(lane>>4)*4+reg (m89-verified)
#pragma unroll
  for (int mi = 0; mi < 4; ++mi) {
    const int m = bm + wr * 64 + mi * 16 + lk * 4;
#pragma unroll
    for (int ni = 0; ni < 4; ++ni) {
      const int n = bn + wc * 64 + ni * 16 + lm;
      if (n < N) {
        const float bv = bias[n];
        float* cp = C + (size_t)m * ldc + n;
#pragma unroll
        for (int r = 0; r < 4; ++r)
          cp[(size_t)r * ldc] = acc[mi][ni][r] + bv;
      }
    }
  }
}

// ------------------------- init: cur = cls (split only; h written by combine_first) -------------------------
__global__ __launch_bounds__(256) void init_state_kernel(
    const float* __restrict__ cls,
    u16* __restrict__ cur_hi, u16* __restrict__ cur_lo) {
  int idx = blockIdx.x * blockDim.x + threadIdx.x;
  if (idx >= 2 * BH) return;
  int rem = idx % BH;
  u16 h, l;
  split_bf16(cls[rem], h, l);
  cur_hi[idx] = h; cur_lo[idx] = l;
}

// ------------------------- GRU combine, j=0: gh == bhh exactly (h=0) -------------------------
__global__ __launch_bounds__(256) void gru_combine_first(
    const float* __restrict__ gi2, const float* __restrict__ gbhh, float* __restrict__ h2,
    u16* __restrict__ h_hi, u16* __restrict__ h_lo) {
  int idx = blockIdx.x * blockDim.x + threadIdx.x;
  if (idx >= 2 * BH) return;
  int e = idx / BH, rem = idx % BH;
  int b = rem / H_DIM, c = rem - b * H_DIM;
  const float* gib = gi2 + ((size_t)e * B_DIM + b) * 3 * H_DIM;
  const float* bb = gbhh + (size_t)e * 3 * H_DIM;
  float ir = gib[c], iz = gib[H_DIM + c], inn = gib[2 * H_DIM + c];
  float hr = bb[c], hz = bb[H_DIM + c], hn = bb[2 * H_DIM + c];
  float r = sigmoidf_(ir + hr);
  float z = sigmoidf_(iz + hz);
  float n = tanhf(inn + r * hn);
  float hv = (1.0f - z) * n + z * 0.0f;
  h2[idx] = hv;
  u16 h, l;
  split_bf16(hv, h, l);
  h_hi[idx] = h; h_lo[idx] = l;
}

// ------------------------- GRU gate combine (both heads) + h split -------------------------
__global__ __launch_bounds__(256) void gru_combine_kernel(
    const float* __restrict__ gi2, const float* __restrict__ gh2, float* __restrict__ h2,
    u16* __restrict__ h_hi, u16* __restrict__ h_lo) {
  int idx = blockIdx.x * blockDim.x + threadIdx.x;
  if (idx >= 2 * BH) return;
  int e = idx / BH, rem = idx % BH;
  int b = rem / H_DIM, c = rem - b * H_DIM;
  const float* gib = gi2 + ((size_t)e * B_DIM + b) * 3 * H_DIM;
  const float* ghb = gh2 + ((size_t)e * B_DIM + b) * 3 * H_DIM;
  float ir = gib[c], iz = gib[H_DIM + c], inn = gib[2 * H_DIM + c];
  float hr = ghb[c], hz = ghb[H_DIM + c], hn = ghb[2 * H_DIM + c];
  float r = sigmoidf_(ir + hr);
  float z = sigmoidf_(iz + hz);
  float n = tanhf(inn + r * hn);
  float hv = (1.0f - z) * n + z * h2[idx];
  h2[idx] = hv;
  u16 h, l;
  split_bf16(hv, h, l);
  h_hi[idx] = h; h_lo[idx] = l;
}

// ------------------------- cur_in = cls + ae_w[ind] (both heads), split output -------------------------
__global__ __launch_bounds__(256) void curin_kernel(
    const float* __restrict__ cls, const float* __restrict__ ae_w,
    const int* __restrict__ indb, int j,
    u16* __restrict__ cur_hi, u16* __restrict__ cur_lo) {
  int idx = blockIdx.x * blockDim.x + threadIdx.x;
  if (idx >= 2 * BH) return;
  int e = idx / BH, rem = idx % BH;
  int b = rem / H_DIM, c = rem - b * H_DIM;
  int ind = indb[(e * NSTEPS + j) * B_DIM + b];
  float v = cls[rem] + ae_w[(size_t)ind * H_DIM + c];
  u16 h, l;
  split_bf16(v, h, l);
  cur_hi[idx] = h; cur_lo[idx] = l;
}

// ------------------------- sampling (both heads), in-place on probs rows -------------------------
#define STH 256
#define PER_TH 20  // ceil(5001/256)

__global__ __launch_bounds__(STH) void sample_kernel(
    float* __restrict__ probs, const int* __restrict__ x_mask,
    int* __restrict__ indb, int j, uint4 keys) {
  int b = blockIdx.x;
  int e = blockIdx.y;
  int t = threadIdx.x;
  uint32_t k0 = (e == 0) ? keys.x : keys.z;
  uint32_t k1 = (e == 0) ? keys.y : keys.w;
  __shared__ float rv[STH];
  __shared__ int ri[STH];
  __shared__ int s_ind;

  float* prow = probs + (((size_t)b * NHEADS + e) * NSTEPS + j) * A_DIM;
  const int* mrow = x_mask + (size_t)b * A_DIM;

  int prev[3];
  bool dead = false;
  for (int tt = 0; tt < j; ++tt) {
    prev[tt] = indb[(e * NSTEPS + tt) * B_DIM + b];
    if (prev[tt] == 0) dead = true;
  }

  bool rowany = true;
  if (j == 0) {
    int any = 0;
    for (int a = t; a < A_DIM; a += STH) any |= mrow[a];
    ri[t] = any; __syncthreads();
    for (int s = STH / 2; s > 0; s >>= 1) {
      if (t < s) ri[t] |= ri[t + s];
      __syncthreads();
    }
    rowany = (ri[0] != 0);
    __syncthreads();
  }

  float v[PER_TH];
  float lmax = -3.0e38f;
#pragma unroll
  for (int s = 0; s < PER_TH; ++s) {
    int a = t + s * STH;
    float val = -3.0e38f;
    if (a < A_DIM) {
      int m;
      if (j == 0) {
        m = (a == 0) ? (rowany ? mrow[0] : 1) : mrow[a];
      } else if (a == 0) {
        m = 1;
      } else if (dead) {
        m = 0;
      } else {
        m = mrow[a];
        if (m) {
          for (int tt = 0; tt < j; ++tt)
            if (prev[tt] == a) { m = 0; break; }
        }
      }
      if (m > 0)
        val = prow[a] + gumbel_noise(k0, k1, (uint32_t)(b * A_DIM + a));
    }
    v[s] = val;
    lmax = fmaxf(lmax, val);
  }

  rv[t] = lmax; __syncthreads();
  for (int s = STH / 2; s > 0; s >>= 1) {
    if (t < s) rv[t] = fmaxf(rv[t], rv[t + s]);
    __syncthreads();
  }
  float m = rv[0]; __syncthreads();

  float lsum = 0.0f;
#pragma unroll
  for (int s = 0; s < PER_TH; ++s) {
    int a = t + s * STH;
    float ev = (a < A_DIM && v[s] > -1.0e37f) ? expf(v[s] - m) : 0.0f;
    v[s] = ev; lsum += ev;
  }
  rv[t] = lsum; __syncthreads();
  for (int s = STH / 2; s > 0; s >>= 1) {
    if (t < s) rv[t] += rv[t + s];
    __syncthreads();
  }
  float ssum = rv[0]; __syncthreads();

  float besty = -1.0f; int besti = A_DIM;
#pragma unroll
  for (int s = 0; s < PER_TH; ++s) {
    int a = t + s * STH;
    if (a < A_DIM) {
      float y = v[s] / ssum;
      if (y > besty) { besty = y; besti = a; }
    }
  }
  rv[t] = besty; ri[t] = besti; __syncthreads();
  for (int s = STH / 2; s > 0; s >>= 1) {
    if (t < s) {
      float y2 = rv[t + s]; int i2 = ri[t + s];
      if (y2 > rv[t] || (y2 == rv[t] && i2 < ri[t])) { rv[t] = y2; ri[t] = i2; }
    }
    __syncthreads();
  }
  if (t == 0) { s_ind = ri[0]; indb[(e * NSTEPS + j) * B_DIM + b] = ri[0]; }
  __syncthreads();
  int ind = s_ind;

  for (int a = t; a < A_DIM; a += STH) prow[a] = (a == ind) ? 1.0f : 0.0f;
}

// ------------------------- per-head consequent estimator (both heads) -------------------------
__global__ __launch_bounds__(256) void head_final_kernel(
    const int* __restrict__ indb, const float* __restrict__ Wmu,
    const float* __restrict__ bmu, const float* __restrict__ Wcov,
    const float* __restrict__ bcov, const float* __restrict__ alpha,
    float* __restrict__ matcp) {
  int idx = blockIdx.x * blockDim.x + threadIdx.x;
  if (idx >= NHEADS * B_DIM) return;
  int e = idx / B_DIM, b = idx - e * B_DIM;
  float a0 = 0.0f, a1 = 0.0f, ac = 0.0f;
  for (int j = 0; j < NSTEPS; ++j) {
    int ind = indb[(e * NSTEPS + j) * B_DIM + b];
    a0 += 0.25f * Wmu[(size_t)ind * C_DIM + 0];
    a1 += 0.25f * Wmu[(size_t)ind * C_DIM + 1];
    ac += 0.25f * Wcov[ind];
  }
  float mu0 = sigmoidf_(a0 + bmu[0]);
  float mu1 = sigmoidf_(a1 + bmu[1]);
  float cov = sigmoidf_(ac + bcov[0]);
  float n = cov * 56000.0f;
  float sf = alpha[0] / n;
  float denom = 1.0f + 2.0f * sf;
  matcp[((size_t)b * NHEADS + e) * C_DIM + 0] = (mu0 + sf) / denom;
  matcp[((size_t)b * NHEADS + e) * C_DIM + 1] = (mu1 + sf) / denom;
}

__global__ __launch_bounds__(256) void final_out_kernel(
    const float* __restrict__ matcp, float* __restrict__ out) {
  int idx = blockIdx.x * blockDim.x + threadIdx.x;
  if (idx >= B_DIM * C_DIM) return;
  int b = idx / C_DIM, c = idx - b * C_DIM;
  float s = matcp[((size_t)b * NHEADS + 0) * C_DIM + c] +
            matcp[((size_t)b * NHEADS + 1) * C_DIM + c];
  out[idx] = logf(s * 0.5f);
}

// ------------------------- orchestration -------------------------
extern "C" void kernel_launch(void* const* d_in, const int* in_sizes, int n_in,
                              void* d_out, int out_size, void* d_ws, size_t ws_size,
                              hipStream_t stream) {
  const float* x     = (const float*)d_in[0];
  const int*   xmask = (const int*)d_in[1];
  const float* W1 = (const float*)d_in[2];  const float* b1 = (const float*)d_in[3];
  const float* W2 = (const float*)d_in[4];  const float* b2 = (const float*)d_in[5];
  const float* W3 = (const float*)d_in[6];  const float* b3 = (const float*)d_in[7];
  const float* gWih = (const float*)d_in[8];  const float* gWhh = (const float*)d_in[9];
  const float* gbih = (const float*)d_in[10]; const float* gbhh = (const float*)d_in[11];
  const float* hW = (const float*)d_in[12];   const float* hb = (const float*)d_in[13];
  const float* ae_w = (const float*)d_in[14];
  const float* Wmu  = (const float*)d_in[15]; const float* bmu  = (const float*)d_in[16];
  const float* Wcov = (const float*)d_in[17]; const float* bcov = (const float*)d_in[18];
  const float* alpha = (const float*)d_in[19];

  float* out = (float*)d_out;
  float* probs = out + (size_t)B_DIM * C_DIM;                       // [B, 2, 4, A]
  float* matcp = probs + (size_t)B_DIM * NHEADS * NSTEPS * A_DIM;   // [B, 2, C]

  const int HG = 3 * H_DIM;   // 2304
  uint8_t* wsp = (uint8_t*)d_ws;
  auto alloc = [&](size_t bytes) {
    uint8_t* p = wsp;
    wsp += (bytes + 255) & ~(size_t)255;
    return p;
  };
  float* cls  = (float*)alloc((size_t)BH * 4);
  float* h2   = (float*)alloc((size_t)2 * BH * 4);
  float* gi2  = (float*)alloc((size_t)2 * B_DIM * HG * 4);
  float* gh2  = (float*)alloc((size_t)2 * B_DIM * HG * 4);   // also: MLP split-K partials (6*BH floats)
  u16* h_hi   = (u16*)alloc((size_t)2 * BH * 2);
  u16* h_lo   = (u16*)alloc((size_t)2 * BH * 2);
  u16* cur_hi = (u16*)alloc((size_t)2 * BH * 2);
  u16* cur_lo = (u16*)alloc((size_t)2 * BH * 2);
  u16* WihT_h = (u16*)alloc((size_t)2 * HG * H_DIM * 2);
  u16* WihT_l = (u16*)alloc((size_t)2 * HG * H_DIM * 2);
  u16* WhhT_h = (u16*)alloc((size_t)2 * HG * H_DIM * 2);
  u16* WhhT_l = (u16*)alloc((size_t)2 * HG * H_DIM * 2);
  u16* hWT_h  = (u16*)alloc((size_t)2 * A_DIM * H_DIM * 2);
  u16* hWT_l  = (u16*)alloc((size_t)2 * A_DIM * H_DIM * 2);
  int* indb   = (int*)alloc((size_t)NHEADS * NSTEPS * B_DIM * 4);
  float* parts = gh2;         // 6*BH floats == 2*B*HG floats exactly
  float* t1 = gi2;            // MLP temps (gi2 free pre-loop)
  float* t2 = gi2 + BH;

  dim3 blk(256);

  // weight transpose+split (once per launch; weights constant)
  transpose_split<<<dim3(HG / 32, H_DIM / 32, 2), blk, 0, stream>>>(
      gWih, WihT_h, WihT_l, H_DIM, HG, (size_t)H_DIM * HG, (size_t)HG * H_DIM);
  transpose_split<<<dim3(HG / 32, H_DIM / 32, 2), blk, 0, stream>>>(
      gWhh, WhhT_h, WhhT_l, H_DIM, HG, (size_t)H_DIM * HG, (size_t)HG * H_DIM);
  transpose_split<<<dim3((A_DIM + 31) / 32, H_DIM / 32, 2), blk, 0, stream>>>(
      hW, hWT_h, hWT_l, H_DIM, A_DIM, (size_t)H_DIM * A_DIM, (size_t)A_DIM * H_DIM);

  // MLP (fp32 exact, split-K): cls = (relu(relu(x@W1+b1)@W2+b2))@W3 + b3
  const int MN = B_DIM * H_DIM;
  gemm_splitk<<<dim3(H_DIM / 64, B_DIM / 64, 4), blk, 0, stream>>>(
      x, W1, parts, B_DIM, H_DIM, DIN, 128);
  reduce_bias_act<<<(MN + 255) / 256, blk, 0, stream>>>(parts, b1, t1, B_DIM, H_DIM, 4, 1);
  gemm_splitk<<<dim3(H_DIM / 64, B_DIM / 64, 6), blk, 0, stream>>>(
      t1, W2, parts, B_DIM, H_DIM, H_DIM, 128);
  reduce_bias_act<<<(MN + 255) / 256, blk, 0, stream>>>(parts, b2, t2, B_DIM, H_DIM, 6, 1);
  gemm_splitk<<<dim3(H_DIM / 64, B_DIM / 64, 6), blk, 0, stream>>>(
      t2, W3, parts, B_DIM, H_DIM, H_DIM, 128);
  reduce_bias_act<<<(MN + 255) / 256, blk, 0, stream>>>(parts, b3, cls, B_DIM, H_DIM, 6, 0);

  init_state_kernel<<<(2 * BH + 255) / 256, blk, 0, stream>>>(cls, cur_hi, cur_lo);

  // host-side key schedule: key(42) -> fold_in(head) -> fold_in(step)
  uint32_t bk0 = 0u, bk1 = 42u;
  uint32_t hk[2][2];
  threefry2x32(bk0, bk1, 0u, 0u, hk[0][0], hk[0][1]);
  threefry2x32(bk0, bk1, 0u, 1u, hk[1][0], hk[1][1]);

  for (int j = 0; j < NSTEPS; ++j) {
    if (j == 0) {
      // h == 0  =>  gh == bhh exactly; only the gi GEMMs are needed (z=2)
      GemmS gb;
      for (int head = 0; head < NHEADS; ++head) {
        gb.Ah[head] = cur_hi + (size_t)head * BH;
        gb.Al[head] = cur_lo + (size_t)head * BH;
        gb.Bh[head] = WihT_h + (size_t)head * HG * H_DIM;
        gb.Bl[head] = WihT_l + (size_t)head * HG * H_DIM;
        gb.bias[head] = gbih + (size_t)head * HG;
        gb.C[head] = gi2 + (size_t)head * B_DIM * HG;
        gb.Ah[head + 2] = gb.Ah[head]; gb.Al[head + 2] = gb.Al[head];
        gb.Bh[head + 2] = gb.Bh[head]; gb.Bl[head + 2] = gb.Bl[head];
        gb.bias[head + 2] = gb.bias[head]; gb.C[head + 2] = gb.C[head];
      }
      gemm_mfma<<<dim3((HG / 128) * (B_DIM / 128), 2), blk, 0, stream>>>(
          gb, H_DIM, HG, HG, (long long)HG, HG / 128, B_DIM / 128);
      gru_combine_first<<<(2 * BH + 255) / 256, blk, 0, stream>>>(gi2, gbhh, h2, h_hi, h_lo);
    } else {
      // gates GEMM, z=4: {h0:gi, h0:gh, h1:gi, h1:gh}
      GemmS gb;
      for (int head = 0; head < NHEADS; ++head) {
        gb.Ah[head * 2 + 0] = cur_hi + (size_t)head * BH;
        gb.Al[head * 2 + 0] = cur_lo + (size_t)head * BH;
        gb.Bh[head * 2 + 0] = WihT_h + (size_t)head * HG * H_DIM;
        gb.Bl[head * 2 + 0] = WihT_l + (size_t)head * HG * H_DIM;
        gb.bias[head * 2 + 0] = gbih + (size_t)head * HG;
        gb.C[head * 2 + 0] = gi2 + (size_t)head * B_DIM * HG;
        gb.Ah[head * 2 + 1] = h_hi + (size_t)head * BH;
        gb.Al[head * 2 + 1] = h_lo + (size_t)head * BH;
        gb.Bh[head * 2 + 1] = WhhT_h + (size_t)head * HG * H_DIM;
        gb.Bl[head * 2 + 1] = WhhT_l + (size_t)head * HG * H_DIM;
        gb.bias[head * 2 + 1] = gbhh + (size_t)head * HG;
        gb.C[head * 2 + 1] = gh2 + (size_t)head * B_DIM * HG;
      }
      gemm_mfma<<<dim3((HG / 128) * (B_DIM / 128), 4), blk, 0, stream>>>(
          gb, H_DIM, HG, HG, (long long)HG, HG / 128, B_DIM / 128);
      gru_combine_kernel<<<(2 * BH + 255) / 256, blk, 0, stream>>>(gi2, gh2, h2, h_hi, h_lo);
    }

    // logits GEMM, z=2: N=5001 (40 n-blocks), C into probs rows
    GemmS lb;
    for (int head = 0; head < NHEADS; ++head) {
      lb.Ah[head] = h_hi + (size_t)head * BH;
      lb.Al[head] = h_lo + (size_t)head * BH;
      lb.Bh[head] = hWT_h + (size_t)head * A_DIM * H_DIM;
      lb.Bl[head] = hWT_l + (size_t)head * A_DIM * H_DIM;
      lb.bias[head] = hb + (size_t)head * A_DIM;
      lb.C[head] = probs + (size_t)(head * NSTEPS + j) * A_DIM;
      lb.Ah[head + 2] = lb.Ah[head]; lb.Al[head + 2] = lb.Al[head];
      lb.Bh[head + 2] = lb.Bh[head]; lb.Bl[head + 2] = lb.Bl[head];
      lb.bias[head + 2] = lb.bias[head]; lb.C[head + 2] = lb.C[head];
    }
    gemm_mfma<<<dim3(40 * (B_DIM / 128), 2), blk, 0, stream>>>(
        lb, H_DIM, A_DIM, A_DIM, (long long)NHEADS * NSTEPS * A_DIM, 40, B_DIM / 128);

    uint32_t s00, s01, s10, s11;
    threefry2x32(hk[0][0], hk[0][1], 0u, (uint32_t)j, s00, s01);
    threefry2x32(hk[1][0], hk[1][1], 0u, (uint32_t)j, s10, s11);
    uint4 keys; keys.x = s00; keys.y = s01; keys.z = s10; keys.w = s11;
    sample_kernel<<<dim3(B_DIM, NHEADS), dim3(STH), 0, stream>>>(probs, xmask, indb, j, keys);

    if (j < NSTEPS - 1)
      curin_kernel<<<(2 * BH + 255) / 256, blk, 0, stream>>>(cls, ae_w, indb, j, cur_hi, cur_lo);
  }

  head_final_kernel<<<(NHEADS * B_DIM + 255) / 256, blk, 0, stream>>>(
      indb, Wmu, bmu, Wcov, bcov, alpha, matcp);
  final_out_kernel<<<(B_DIM * C_DIM + 255) / 256, blk, 0, stream>>>(matcp, out);
}